// Round 4
// baseline (26370.618 us; speedup 1.0000x reference)
//
#include <hip/hip_runtime.h>
#include <hip/hip_bf16.h>

#define NB 8
#define NC 12
#define NH 320
#define NW 320
#define L2LAMF 0.05f
#define SCALE_NORMAL (1.0f/(320.0f*320.0f))
#define SCALE_ADJ (1.0f/320.0f)

__device__ __forceinline__ float2 cmulf(float2 a, float2 b){
  return make_float2(a.x*b.x - a.y*b.y, a.x*b.y + a.y*b.x);
}

// 320-point FFT: radix-5 in regs + 64-point DIF across the wave's lanes.
// Input: v[j] = x[lane + 64*j] (natural order).
// Output: v[k1] holds X[k1 + 5*brev6(lane)].
// S = -1: forward DFT, S = +1: unnormalized inverse.
template<int S>
__device__ __forceinline__ void fft320(float2 v[5], int lane){
  const float PI = 3.14159265358979323846f;
  const float C1 = 0.30901699437494742f, S1 = 0.95105651629515357f;
  const float C2 = -0.80901699437494745f, S2 = 0.58778525229247314f;
  const float2 w5[5] = { make_float2(1.f,0.f), make_float2(C1, S*S1),
                         make_float2(C2, S*S2), make_float2(C2, -S*S2),
                         make_float2(C1, -S*S1) };
  float2 y[5];
  #pragma unroll
  for (int k=0;k<5;k++){
    float2 s = v[0];
    #pragma unroll
    for (int n=1;n<5;n++){
      float2 t = cmulf(v[n], w5[(n*k)%5]);
      s.x += t.x; s.y += t.y;
    }
    y[k] = s;
  }
  float ang = (float)S * (2.f*PI) * (float)lane * (1.f/320.f);
  float sn, cs; __sincosf(ang, &sn, &cs);
  float2 wt = make_float2(cs, sn);
  float2 t2 = wt;
  y[1] = cmulf(y[1], t2);
  t2 = cmulf(t2, wt); y[2] = cmulf(y[2], t2);
  t2 = cmulf(t2, wt); y[3] = cmulf(y[3], t2);
  t2 = cmulf(t2, wt); y[4] = cmulf(y[4], t2);
  #pragma unroll
  for (int h=32; h>=1; h>>=1){
    int j = lane & (h-1);
    bool up = (lane & h) != 0;
    float a2 = (float)S * PI * (float)j / (float)h;
    float ws, wc; __sincosf(a2, &ws, &wc);
    float2 w = make_float2(wc, ws);
    #pragma unroll
    for (int q=0;q<5;q++){
      float2 a = y[q];
      float2 b;
      b.x = __shfl_xor(a.x, h, 64);
      b.y = __shfl_xor(a.y, h, 64);
      float2 sum = make_float2(a.x+b.x, a.y+b.y);
      float2 dif = make_float2(b.x-a.x, b.y-a.y);
      float2 rot = cmulf(dif, w);
      y[q] = up ? rot : sum;
    }
  }
  #pragma unroll
  for (int q=0;q<5;q++) v[q] = y[q];
}

// ---------- coil-mult + (-1)^{h+w} + forward row FFT (G batches from b0) ----------
__global__ __launch_bounds__(512) void k_rowF(const float2* __restrict__ xin,
                                              const float2* __restrict__ maps,
                                              float2* __restrict__ K, int b0){
  __shared__ float2 lds[8][321];
  int tid = threadIdx.x; int wid = tid >> 6; int lane = tid & 63;
  int row = blockIdx.x * 8 + wid;            // over G*NC*NH
  int h = row % NH; int bc = row / NH; int c = bc % NC; int bg = bc / NC;
  int b = b0 + bg;
  const float2* xr = xin + ((size_t)b*NH + h)*NW;
  const float2* mr = maps + (((size_t)b*NC + c)*NH + h)*NW;
  float2 v[5];
  #pragma unroll
  for (int j=0;j<5;j++){
    int n = lane + 64*j;
    float2 t = cmulf(mr[n], xr[n]);
    float sg = ((h + n) & 1) ? -1.f : 1.f;
    v[j] = make_float2(t.x*sg, t.y*sg);
  }
  fft320<-1>(v, lane);
  int br = __brev((unsigned)lane) >> 26;
  #pragma unroll
  for (int k1=0;k1<5;k1++) lds[wid][k1 + 5*br] = v[k1];   // wave-local unscramble
  float2* Kr = K + (((size_t)(bg*NC + c))*NH + h)*NW;
  #pragma unroll
  for (int j=0;j<5;j++){ int n = lane + 64*j; Kr[n] = lds[wid][n]; }
}

// ---------- column FFT -> mask*scale -> column IFFT (in place, G batches) ----------
__global__ __launch_bounds__(512) void k_colFMI(float2* __restrict__ K,
                                                const float* __restrict__ masks, int b0){
  __shared__ float2 tile[8][321];
  int tid = threadIdx.x;
  int bid = blockIdx.x;                     // bg*NC*40 + c*40 + ct
  int ct = bid % 40; int c = (bid/40) % NC; int bg = bid/(40*NC);
  int b = b0 + bg;
  int col0 = ct * 8;
  float2* base = K + ((size_t)(bg*NC + c))*NH*NW;
  #pragma unroll
  for (int it=0; it<5; it++){
    int e = tid + 512*it; int hh = e >> 3; int ci = e & 7;
    tile[ci][hh] = base[(size_t)hh*NW + col0 + ci];
  }
  __syncthreads();
  int wid = tid >> 6, lane = tid & 63;
  int col = col0 + wid;
  float2 v[5];
  #pragma unroll
  for (int j=0;j<5;j++) v[j] = tile[wid][lane + 64*j];
  fft320<-1>(v, lane);
  int br = __brev((unsigned)lane) >> 26;
  const float* mb = masks + (size_t)b*NH*NW + col;
  #pragma unroll
  for (int k1=0;k1<5;k1++){
    int kh = k1 + 5*br;
    float mv = mb[(size_t)kh*NW] * SCALE_NORMAL;
    v[k1].x *= mv; v[k1].y *= mv;
    tile[wid][kh] = v[k1];
  }
  #pragma unroll
  for (int j=0;j<5;j++) v[j] = tile[wid][lane + 64*j];
  fft320<1>(v, lane);
  #pragma unroll
  for (int k1=0;k1<5;k1++) tile[wid][k1 + 5*br] = v[k1];
  __syncthreads();
  #pragma unroll
  for (int it=0; it<5; it++){
    int e = tid + 512*it; int hh = e >> 3; int ci = e & 7;
    base[(size_t)hh*NW + col0 + ci] = tile[ci][hh];
  }
}

// ---------- adjoint: (-1)^{kh+kw}*mask*(1/320) then column IFFT (G batches) ----------
__global__ __launch_bounds__(512) void k_adjCol(const float2* __restrict__ ksp,
                                                const float* __restrict__ masks,
                                                float2* __restrict__ K, int b0){
  __shared__ float2 tile[8][321];
  int tid = threadIdx.x;
  int bid = blockIdx.x;
  int ct = bid % 40; int c = (bid/40) % NC; int bg = bid/(40*NC);
  int b = b0 + bg;
  int col0 = ct * 8;
  const float2* src = ksp + ((size_t)(b*NC + c))*NH*NW;
  float2* dst = K + ((size_t)(bg*NC + c))*NH*NW;
  #pragma unroll
  for (int it=0; it<5; it++){
    int e = tid + 512*it; int hh = e >> 3; int ci = e & 7;
    tile[ci][hh] = src[(size_t)hh*NW + col0 + ci];
  }
  __syncthreads();
  int wid = tid >> 6, lane = tid & 63;
  int col = col0 + wid;
  const float* mb = masks + (size_t)b*NH*NW + col;
  float2 v[5];
  #pragma unroll
  for (int j=0;j<5;j++){
    int hh = lane + 64*j;
    float2 t = tile[wid][hh];
    float mv = mb[(size_t)hh*NW] * (((hh + col) & 1) ? -SCALE_ADJ : SCALE_ADJ);
    v[j] = make_float2(t.x*mv, t.y*mv);
  }
  fft320<1>(v, lane);
  int br = __brev((unsigned)lane) >> 26;
  #pragma unroll
  for (int k1=0;k1<5;k1++) tile[wid][k1 + 5*br] = v[k1];
  __syncthreads();
  #pragma unroll
  for (int it=0; it<5; it++){
    int e = tid + 512*it; int hh = e >> 3; int ci = e & 7;
    dst[(size_t)hh*NW + col0 + ci] = tile[ci][hh];
  }
}

// ---------- row IFFT + (-1)^{h+w} + conj(maps) combine (+ lam*p, pAp) ----------
template<bool AOP>
__global__ __launch_bounds__(256) void k_rowIC(const float2* __restrict__ K,
                                               const float2* __restrict__ maps,
                                               const float2* __restrict__ p,
                                               float2* __restrict__ out,
                                               float* __restrict__ pAp, int b0){
  __shared__ float2 acc_lds[4][321];
  __shared__ float red[4];
  int tid = threadIdx.x; int wid = tid >> 6; int lane = tid & 63;
  int bg = blockIdx.x / NH; int h = blockIdx.x % NH;
  int b = b0 + bg;
  int br = __brev((unsigned)lane) >> 26;
  float2 acc[5];
  #pragma unroll
  for (int k1=0;k1<5;k1++) acc[k1] = make_float2(0.f, 0.f);
  for (int c = wid; c < NC; c += 4){
    const float2* Kr = K + (((size_t)(bg*NC + c))*NH + h)*NW;
    float2 v[5];
    #pragma unroll
    for (int j=0;j<5;j++) v[j] = Kr[lane + 64*j];
    fft320<1>(v, lane);
    const float2* mr = maps + (((size_t)b*NC + c)*NH + h)*NW;
    #pragma unroll
    for (int k1=0;k1<5;k1++){
      int n = k1 + 5*br;
      float2 m = mr[n];
      float2 t = make_float2(m.x*v[k1].x + m.y*v[k1].y, m.x*v[k1].y - m.y*v[k1].x);
      float sg = ((h + n) & 1) ? -1.f : 1.f;
      acc[k1].x += t.x*sg; acc[k1].y += t.y*sg;
    }
  }
  #pragma unroll
  for (int k1=0;k1<5;k1++) acc_lds[wid][k1 + 5*br] = acc[k1];
  __syncthreads();
  float partial = 0.f;
  const float2* prow = AOP ? (p + ((size_t)b*NH + h)*NW) : (const float2*)nullptr;
  float2* orow = out + ((size_t)b*NH + h)*NW;
  for (int n = tid; n < NW; n += 256){
    float2 s;
    s.x = acc_lds[0][n].x + acc_lds[1][n].x + acc_lds[2][n].x + acc_lds[3][n].x;
    s.y = acc_lds[0][n].y + acc_lds[1][n].y + acc_lds[2][n].y + acc_lds[3][n].y;
    if (AOP){
      float2 pv = prow[n];
      s.x += L2LAMF * pv.x; s.y += L2LAMF * pv.y;
      partial += pv.x*s.x + pv.y*s.y;
    }
    orow[n] = s;
  }
  if (AOP){
    #pragma unroll
    for (int o=32;o>0;o>>=1) partial += __shfl_down(partial, o, 64);
    if (lane == 0) red[wid] = partial;
    __syncthreads();
    if (tid == 0) atomicAdd(&pAp[b], red[0]+red[1]+red[2]+red[3]);
  }
}

// ---------- Fully-fused denoiser: rhs = xadj + lam*(x + CNN(x)), 8x8 tiles ----------
// xr holds xadj on entry, rhs on exit (elementwise in-place).
__global__ __launch_bounds__(256) void k_denoise(
    const float2* __restrict__ xin,
    const float* __restrict__ w1, const float* __restrict__ b1,
    const float* __restrict__ w2, const float* __restrict__ b2,
    const float* __restrict__ w3, const float* __restrict__ b3,
    float2* __restrict__ xr){
  __shared__ float2 sx[14][15];
  __shared__ __hip_bfloat16 sh1[64][12][13];
  __shared__ __hip_bfloat16 sh2[64][10][11];
  __shared__ float sw2[64*4*9];
  __shared__ float sw1[64*18];
  __shared__ float sw3[2*64*9];
  __shared__ float sb1[64], sb2[64];
  int tid = threadIdx.x;
  int b = blockIdx.z; int ox0 = blockIdx.x*8, oy0 = blockIdx.y*8;
  for (int i=tid;i<64*18;i+=256) sw1[i]=w1[i];
  for (int i=tid;i<2*64*9;i+=256) sw3[i]=w3[i];
  if (tid<64){ sb1[tid]=b1[tid]; sb2[tid]=b2[tid]; }
  for (int i=tid;i<14*14;i+=256){
    int y=i/14, x=i%14; int gy=oy0-3+y, gx=ox0-3+x;
    float2 t=make_float2(0.f,0.f);
    if (gy>=0&&gy<NH&&gx>=0&&gx<NW) t=xin[((size_t)b*NH+gy)*NW+gx];
    sx[y][x]=t;
  }
  __syncthreads();
  // conv1 -> sh1 (12x12 region, zero outside image so conv2's SAME-pad matches ref)
  if (tid < 144){
    int y=tid/12, x=tid%12;
    int gy=oy0-2+y, gx=ox0-2+x;
    bool in = (gy>=0&&gy<NH&&gx>=0&&gx<NW);
    float acc[64];
    #pragma unroll
    for(int o=0;o<64;o++) acc[o]=sb1[o];
    #pragma unroll
    for(int dy=0;dy<3;dy++)
    #pragma unroll
    for(int dx=0;dx<3;dx++){
      float2 iv = sx[y+dy][x+dx];
      int tap=dy*3+dx;
      #pragma unroll
      for(int o=0;o<64;o++) acc[o]+= iv.x*sw1[o*18+tap]+iv.y*sw1[o*18+9+tap];
    }
    #pragma unroll
    for(int o=0;o<64;o++)
      sh1[o][y][x] = __float2bfloat16(in ? fmaxf(acc[o],0.f) : 0.f);
  }
  __syncthreads();
  // conv2 -> sh2 (10x10): 4 waves x 16 oc, lanes cover 100 px in 2 chunks
  int lane = tid&63, ocg = tid>>6;
  float acc2[2][16];
  #pragma unroll
  for(int q=0;q<2;q++)
    #pragma unroll
    for(int o=0;o<16;o++) acc2[q][o]=0.f;
  for (int cc=0; cc<16; cc++){          // 4 input channels per chunk
    for (int i=tid;i<64*4*9;i+=256){
      int o=i/36, r=i%36;
      sw2[i] = w2[((size_t)o*64 + cc*4 + r/9)*9 + (r%9)];
    }
    __syncthreads();
    #pragma unroll
    for(int icl=0;icl<4;icl++){
      int ic = cc*4+icl;
      #pragma unroll
      for(int q=0;q<2;q++){
        int p = lane + q*64;
        if (p<100){
          int y=p/10, x=p%10;
          #pragma unroll
          for(int dy=0;dy<3;dy++)
          #pragma unroll
          for(int dx=0;dx<3;dx++){
            float v = __bfloat162float(sh1[ic][y+dy][x+dx]);
            int tap=icl*9+dy*3+dx;
            #pragma unroll
            for(int o=0;o<16;o++)
              acc2[q][o] += v * sw2[(ocg*16+o)*36 + tap];
          }
        }
      }
    }
    __syncthreads();
  }
  #pragma unroll
  for(int q=0;q<2;q++){
    int p=lane+q*64;
    if (p<100){
      int y=p/10, x=p%10;
      int gy=oy0-1+y, gx=ox0-1+x;
      bool in=(gy>=0&&gy<NH&&gx>=0&&gx<NW);
      #pragma unroll
      for(int o=0;o<16;o++)
        sh2[ocg*16+o][y][x]=__float2bfloat16(in?fmaxf(acc2[q][o]+sb2[ocg*16+o],0.f):0.f);
    }
  }
  __syncthreads();
  // conv3 (8x8, 2 ch): 4 ic-groups of 16, partials in LDS scratch (reuse sh1)
  float* scr = (float*)&sh1[0][0][0];
  {
    int p = tid & 63; int icg = tid >> 6;
    int y=p/8, x=p%8;
    float a0=0.f, a1=0.f;
    for (int icl=0; icl<16; icl++){
      int ic = icg*16+icl;
      #pragma unroll
      for(int dy=0;dy<3;dy++)
      #pragma unroll
      for(int dx=0;dx<3;dx++){
        float v = __bfloat162float(sh2[ic][y+dy][x+dx]);
        a0 += v*sw3[ic*9+dy*3+dx];
        a1 += v*sw3[576+ic*9+dy*3+dx];
      }
    }
    scr[(icg*64+p)*2+0]=a0;
    scr[(icg*64+p)*2+1]=a1;
  }
  __syncthreads();
  if (tid<64){
    int y=tid/8, x=tid%8;
    float a0 = scr[tid*2]+scr[(64+tid)*2]+scr[(128+tid)*2]+scr[(192+tid)*2];
    float a1 = scr[tid*2+1]+scr[(64+tid)*2+1]+scr[(128+tid)*2+1]+scr[(192+tid)*2+1];
    int gy=oy0+y, gx=ox0+x;
    size_t g=((size_t)b*NH+gy)*NW+gx;
    float2 xa=xr[g]; float2 xv=xin[g];
    float2 o;
    o.x = xa.x + L2LAMF*(xv.x + a0 + b3[0]);
    o.y = xa.y + L2LAMF*(xv.y + a1 + b3[1]);
    xr[g]=o;
  }
}

// ---------- CG glue ----------
__global__ __launch_bounds__(256) void k_cginit(const float2* __restrict__ rhs,
                                                const float2* __restrict__ Ax0,
                                                const float2* __restrict__ x0,
                                                float2* __restrict__ x,
                                                float2* __restrict__ r,
                                                float2* __restrict__ p,
                                                float* __restrict__ rs){
  __shared__ float red[4];
  int tid = threadIdx.x;
  int b = blockIdx.x / 400; int e = (blockIdx.x % 400)*256 + tid;
  size_t g = (size_t)b*NH*NW + e;
  float2 rh = rhs[g], ax = Ax0[g];
  float2 rv = make_float2(rh.x - ax.x, rh.y - ax.y);
  r[g] = rv; p[g] = rv; x[g] = x0[g];
  float partial = rv.x*rv.x + rv.y*rv.y;
  int lane = tid & 63, wid = tid >> 6;
  #pragma unroll
  for (int o=32;o>0;o>>=1) partial += __shfl_down(partial, o, 64);
  if (lane == 0) red[wid] = partial;
  __syncthreads();
  if (tid == 0) atomicAdd(&rs[b], red[0]+red[1]+red[2]+red[3]);
}

__global__ __launch_bounds__(256) void k_cgupdate(float2* __restrict__ x,
                                                  float2* __restrict__ r,
                                                  const float2* __restrict__ p,
                                                  const float2* __restrict__ Ap,
                                                  const float* __restrict__ rs_old,
                                                  const float* __restrict__ pAp,
                                                  float* __restrict__ rs_new){
  __shared__ float red[4];
  int tid = threadIdx.x;
  int b = blockIdx.x / 400; int e = (blockIdx.x % 400)*256 + tid;
  size_t g = (size_t)b*NH*NW + e;
  float alpha = rs_old[b] / pAp[b];
  float2 xv = x[g], pv = p[g], rv = r[g], av = Ap[g];
  xv.x += alpha*pv.x; xv.y += alpha*pv.y;
  rv.x -= alpha*av.x; rv.y -= alpha*av.y;
  x[g] = xv; r[g] = rv;
  float partial = rv.x*rv.x + rv.y*rv.y;
  int lane = tid & 63, wid = tid >> 6;
  #pragma unroll
  for (int o=32;o>0;o>>=1) partial += __shfl_down(partial, o, 64);
  if (lane == 0) red[wid] = partial;
  __syncthreads();
  if (tid == 0) atomicAdd(&rs_new[b], red[0]+red[1]+red[2]+red[3]);
}

__global__ __launch_bounds__(256) void k_cgp(float2* __restrict__ p,
                                             const float2* __restrict__ r,
                                             const float* __restrict__ rs_new,
                                             const float* __restrict__ rs_old){
  int tid = threadIdx.x;
  int b = blockIdx.x / 400; int e = (blockIdx.x % 400)*256 + tid;
  size_t g = (size_t)b*NH*NW + e;
  float beta = rs_new[b] / rs_old[b];
  float2 rv = r[g], pv = p[g];
  p[g] = make_float2(rv.x + beta*pv.x, rv.y + beta*pv.y);
}

extern "C" void kernel_launch(void* const* d_in, const int* in_sizes, int n_in,
                              void* d_out, int out_size, void* d_ws, size_t ws_size,
                              hipStream_t stream) {
  (void)in_sizes; (void)n_in; (void)out_size;
  const float2* x_in = (const float2*)d_in[0];
  const float2* maps = (const float2*)d_in[1];
  const float*  masks= (const float*)d_in[2];
  const float2* ksp  = (const float2*)d_in[3];
  const float* w1 = (const float*)d_in[4]; const float* b1 = (const float*)d_in[5];
  const float* w2 = (const float*)d_in[6]; const float* b2 = (const float*)d_in[7];
  const float* w3 = (const float*)d_in[8]; const float* b3 = (const float*)d_in[9];
  float2* xout = (float2*)d_out;

  // Workspace budget: 4 image vectors (26.2 MB) + scal + K for G batches.
  const size_t VECB = (size_t)NB*NH*NW*sizeof(float2);       // 6.55 MB
  const size_t PERB = (size_t)NC*NH*NW*sizeof(float2);       // 9.83 MB per batch of K
  auto rnd = [](size_t x){ return (x + 255) & ~(size_t)255; };
  size_t fixed = 4*rnd(VECB) + rnd(4096);
  int G = 8;
  while (G > 1 && fixed + (size_t)G*PERB > ws_size) G >>= 1;

  char* ws = (char*)d_ws;
  size_t off = 0;
  auto alloc = [&](size_t bytes)->void*{ void* p = ws + off; off += rnd(bytes); return p; };
  float2* xr   = (float2*)alloc(VECB);   // xadj on entry to denoiser, rhs after
  float2* Ap   = (float2*)alloc(VECB);
  float2* rbuf = (float2*)alloc(VECB);
  float2* pbuf = (float2*)alloc(VECB);
  float*  scal = (float*)alloc(4096);    // rs[i*8+b], pAp at +64
  float2* K    = (float2*)alloc((size_t)G*PERB);
  hipMemsetAsync(scal, 0, 4096, stream);

  const int gCol = G*NC*40;   // adjCol / colFMI blocks
  const int gRow = G*NC*NH/8; // rowF blocks
  const int gIC  = G*NH;      // rowIC blocks

  // adjoint: xadj -> xr
  for (int b0 = 0; b0 < NB; b0 += G){
    k_adjCol<<<gCol, 512, 0, stream>>>(ksp, masks, K, b0);
    k_rowIC<false><<<gIC, 256, 0, stream>>>(K, maps, nullptr, xr, nullptr, b0);
  }
  // denoiser: xr = xadj + lam*(x + CNN(x)) = rhs
  k_denoise<<<dim3(40,40,8), 256, 0, stream>>>(x_in, w1,b1, w2,b2, w3,b3, xr);
  // Aop(x0) -> Ap
  for (int b0 = 0; b0 < NB; b0 += G){
    k_rowF<<<gRow, 512, 0, stream>>>(x_in, maps, K, b0);
    k_colFMI<<<gCol, 512, 0, stream>>>(K, masks, b0);
    k_rowIC<true><<<gIC, 256, 0, stream>>>(K, maps, x_in, Ap, scal + 64, b0);
  }
  // r = rhs - Ax0; p = r; x = x0; rs0
  k_cginit<<<3200, 256, 0, stream>>>(xr, Ap, x_in, xout, rbuf, pbuf, scal);
  // 6 CG iterations
  for (int i = 1; i <= 6; i++){
    for (int b0 = 0; b0 < NB; b0 += G){
      k_rowF<<<gRow, 512, 0, stream>>>(pbuf, maps, K, b0);
      k_colFMI<<<gCol, 512, 0, stream>>>(K, masks, b0);
      k_rowIC<true><<<gIC, 256, 0, stream>>>(K, maps, pbuf, Ap, scal + 64 + i*8, b0);
    }
    k_cgupdate<<<3200, 256, 0, stream>>>(xout, rbuf, pbuf, Ap,
                                         scal + (i-1)*8, scal + 64 + i*8, scal + i*8);
    if (i < 6)
      k_cgp<<<3200, 256, 0, stream>>>(pbuf, rbuf, scal + i*8, scal + (i-1)*8);
  }
}

// Round 5
// 3919.844 us; speedup vs baseline: 6.7275x; 6.7275x over previous
//
#include <hip/hip_runtime.h>
#include <hip/hip_bf16.h>

#define NB 8
#define NC 12
#define NH 320
#define NW 320
#define L2LAMF 0.05f
#define SCALE_NORMAL (1.0f/(320.0f*320.0f))
#define SCALE_ADJ (1.0f/320.0f)

__device__ __forceinline__ float2 cmulf(float2 a, float2 b){
  return make_float2(a.x*b.x - a.y*b.y, a.x*b.y + a.y*b.x);
}

// 320-point FFT: radix-5 in regs + 64-point DIF across the wave's lanes.
// Input: v[j] = x[lane + 64*j]. Output: v[k1] holds X[k1 + 5*brev6(lane)].
// S = -1 forward, S = +1 unnormalized inverse.
template<int S>
__device__ __forceinline__ void fft320(float2 v[5], int lane){
  const float PI = 3.14159265358979323846f;
  const float C1 = 0.30901699437494742f, S1 = 0.95105651629515357f;
  const float C2 = -0.80901699437494745f, S2 = 0.58778525229247314f;
  const float2 w5[5] = { make_float2(1.f,0.f), make_float2(C1, S*S1),
                         make_float2(C2, S*S2), make_float2(C2, -S*S2),
                         make_float2(C1, -S*S1) };
  float2 y[5];
  #pragma unroll
  for (int k=0;k<5;k++){
    float2 s = v[0];
    #pragma unroll
    for (int n=1;n<5;n++){
      float2 t = cmulf(v[n], w5[(n*k)%5]);
      s.x += t.x; s.y += t.y;
    }
    y[k] = s;
  }
  float ang = (float)S * (2.f*PI) * (float)lane * (1.f/320.f);
  float sn, cs; __sincosf(ang, &sn, &cs);
  float2 wt = make_float2(cs, sn);
  float2 t2 = wt;
  y[1] = cmulf(y[1], t2);
  t2 = cmulf(t2, wt); y[2] = cmulf(y[2], t2);
  t2 = cmulf(t2, wt); y[3] = cmulf(y[3], t2);
  t2 = cmulf(t2, wt); y[4] = cmulf(y[4], t2);
  #pragma unroll
  for (int h=32; h>=1; h>>=1){
    int j = lane & (h-1);
    bool up = (lane & h) != 0;
    float a2 = (float)S * PI * (float)j / (float)h;
    float ws, wc; __sincosf(a2, &ws, &wc);
    float2 w = make_float2(wc, ws);
    #pragma unroll
    for (int q=0;q<5;q++){
      float2 a = y[q];
      float2 b;
      b.x = __shfl_xor(a.x, h, 64);
      b.y = __shfl_xor(a.y, h, 64);
      float2 sum = make_float2(a.x+b.x, a.y+b.y);
      float2 dif = make_float2(b.x-a.x, b.y-a.y);
      float2 rot = cmulf(dif, w);
      y[q] = up ? rot : sum;
    }
  }
  #pragma unroll
  for (int q=0;q<5;q++) v[q] = y[q];
}

// ---------- coil-mult + (-1)^{h+w} + forward row FFT (G batches from b0) ----------
__global__ __launch_bounds__(512) void k_rowF(const float2* __restrict__ xin,
                                              const float2* __restrict__ maps,
                                              float2* __restrict__ K, int b0){
  __shared__ float2 lds[8][321];
  int tid = threadIdx.x; int wid = tid >> 6; int lane = tid & 63;
  int row = blockIdx.x * 8 + wid;
  int h = row % NH; int bc = row / NH; int c = bc % NC; int bg = bc / NC;
  int b = b0 + bg;
  const float2* xr = xin + ((size_t)b*NH + h)*NW;
  const float2* mr = maps + (((size_t)b*NC + c)*NH + h)*NW;
  float2 v[5];
  #pragma unroll
  for (int j=0;j<5;j++){
    int n = lane + 64*j;
    float2 t = cmulf(mr[n], xr[n]);
    float sg = ((h + n) & 1) ? -1.f : 1.f;
    v[j] = make_float2(t.x*sg, t.y*sg);
  }
  fft320<-1>(v, lane);
  int br = __brev((unsigned)lane) >> 26;
  #pragma unroll
  for (int k1=0;k1<5;k1++) lds[wid][k1 + 5*br] = v[k1];
  float2* Kr = K + (((size_t)(bg*NC + c))*NH + h)*NW;
  #pragma unroll
  for (int j=0;j<5;j++){ int n = lane + 64*j; Kr[n] = lds[wid][n]; }
}

// ---------- column FFT -> mask*scale -> column IFFT (in place, G batches) ----------
__global__ __launch_bounds__(512) void k_colFMI(float2* __restrict__ K,
                                                const float* __restrict__ masks, int b0){
  __shared__ float2 tile[8][321];
  int tid = threadIdx.x;
  int bid = blockIdx.x;
  int ct = bid % 40; int c = (bid/40) % NC; int bg = bid/(40*NC);
  int b = b0 + bg;
  int col0 = ct * 8;
  float2* base = K + ((size_t)(bg*NC + c))*NH*NW;
  #pragma unroll
  for (int it=0; it<5; it++){
    int e = tid + 512*it; int hh = e >> 3; int ci = e & 7;
    tile[ci][hh] = base[(size_t)hh*NW + col0 + ci];
  }
  __syncthreads();
  int wid = tid >> 6, lane = tid & 63;
  int col = col0 + wid;
  float2 v[5];
  #pragma unroll
  for (int j=0;j<5;j++) v[j] = tile[wid][lane + 64*j];
  fft320<-1>(v, lane);
  int br = __brev((unsigned)lane) >> 26;
  const float* mb = masks + (size_t)b*NH*NW + col;
  #pragma unroll
  for (int k1=0;k1<5;k1++){
    int kh = k1 + 5*br;
    float mv = mb[(size_t)kh*NW] * SCALE_NORMAL;
    v[k1].x *= mv; v[k1].y *= mv;
    tile[wid][kh] = v[k1];
  }
  #pragma unroll
  for (int j=0;j<5;j++) v[j] = tile[wid][lane + 64*j];
  fft320<1>(v, lane);
  #pragma unroll
  for (int k1=0;k1<5;k1++) tile[wid][k1 + 5*br] = v[k1];
  __syncthreads();
  #pragma unroll
  for (int it=0; it<5; it++){
    int e = tid + 512*it; int hh = e >> 3; int ci = e & 7;
    base[(size_t)hh*NW + col0 + ci] = tile[ci][hh];
  }
}

// ---------- adjoint: (-1)^{kh+kw}*mask*(1/320) then column IFFT (G batches) ----------
__global__ __launch_bounds__(512) void k_adjCol(const float2* __restrict__ ksp,
                                                const float* __restrict__ masks,
                                                float2* __restrict__ K, int b0){
  __shared__ float2 tile[8][321];
  int tid = threadIdx.x;
  int bid = blockIdx.x;
  int ct = bid % 40; int c = (bid/40) % NC; int bg = bid/(40*NC);
  int b = b0 + bg;
  int col0 = ct * 8;
  const float2* src = ksp + ((size_t)(b*NC + c))*NH*NW;
  float2* dst = K + ((size_t)(bg*NC + c))*NH*NW;
  #pragma unroll
  for (int it=0; it<5; it++){
    int e = tid + 512*it; int hh = e >> 3; int ci = e & 7;
    tile[ci][hh] = src[(size_t)hh*NW + col0 + ci];
  }
  __syncthreads();
  int wid = tid >> 6, lane = tid & 63;
  int col = col0 + wid;
  const float* mb = masks + (size_t)b*NH*NW + col;
  float2 v[5];
  #pragma unroll
  for (int j=0;j<5;j++){
    int hh = lane + 64*j;
    float2 t = tile[wid][hh];
    float mv = mb[(size_t)hh*NW] * (((hh + col) & 1) ? -SCALE_ADJ : SCALE_ADJ);
    v[j] = make_float2(t.x*mv, t.y*mv);
  }
  fft320<1>(v, lane);
  int br = __brev((unsigned)lane) >> 26;
  #pragma unroll
  for (int k1=0;k1<5;k1++) tile[wid][k1 + 5*br] = v[k1];
  __syncthreads();
  #pragma unroll
  for (int it=0; it<5; it++){
    int e = tid + 512*it; int hh = e >> 3; int ci = e & 7;
    dst[(size_t)hh*NW + col0 + ci] = tile[ci][hh];
  }
}

// ---------- row IFFT + (-1)^{h+w} + conj(maps) combine (+ lam*p, pAp) ----------
template<bool AOP>
__global__ __launch_bounds__(256) void k_rowIC(const float2* __restrict__ K,
                                               const float2* __restrict__ maps,
                                               const float2* __restrict__ p,
                                               float2* __restrict__ out,
                                               float* __restrict__ pAp, int b0){
  __shared__ float2 acc_lds[4][321];
  __shared__ float red[4];
  int tid = threadIdx.x; int wid = tid >> 6; int lane = tid & 63;
  int bg = blockIdx.x / NH; int h = blockIdx.x % NH;
  int b = b0 + bg;
  int br = __brev((unsigned)lane) >> 26;
  float2 acc[5];
  #pragma unroll
  for (int k1=0;k1<5;k1++) acc[k1] = make_float2(0.f, 0.f);
  for (int c = wid; c < NC; c += 4){
    const float2* Kr = K + (((size_t)(bg*NC + c))*NH + h)*NW;
    float2 v[5];
    #pragma unroll
    for (int j=0;j<5;j++) v[j] = Kr[lane + 64*j];
    fft320<1>(v, lane);
    const float2* mr = maps + (((size_t)b*NC + c)*NH + h)*NW;
    #pragma unroll
    for (int k1=0;k1<5;k1++){
      int n = k1 + 5*br;
      float2 m = mr[n];
      float2 t = make_float2(m.x*v[k1].x + m.y*v[k1].y, m.x*v[k1].y - m.y*v[k1].x);
      float sg = ((h + n) & 1) ? -1.f : 1.f;
      acc[k1].x += t.x*sg; acc[k1].y += t.y*sg;
    }
  }
  #pragma unroll
  for (int k1=0;k1<5;k1++) acc_lds[wid][k1 + 5*br] = acc[k1];
  __syncthreads();
  float partial = 0.f;
  const float2* prow = AOP ? (p + ((size_t)b*NH + h)*NW) : (const float2*)nullptr;
  float2* orow = out + ((size_t)b*NH + h)*NW;
  for (int n = tid; n < NW; n += 256){
    float2 s;
    s.x = acc_lds[0][n].x + acc_lds[1][n].x + acc_lds[2][n].x + acc_lds[3][n].x;
    s.y = acc_lds[0][n].y + acc_lds[1][n].y + acc_lds[2][n].y + acc_lds[3][n].y;
    if (AOP){
      float2 pv = prow[n];
      s.x += L2LAMF * pv.x; s.y += L2LAMF * pv.y;
      partial += pv.x*s.x + pv.y*s.y;
    }
    orow[n] = s;
  }
  if (AOP){
    #pragma unroll
    for (int o=32;o>0;o>>=1) partial += __shfl_down(partial, o, 64);
    if (lane == 0) red[wid] = partial;
    __syncthreads();
    if (tid == 0) atomicAdd(&pAp[b], red[0]+red[1]+red[2]+red[3]);
  }
}

// ---------- Denoiser (split kernels, DEN_G batches per pass) ----------
__global__ __launch_bounds__(256) void k_conv1(const float2* __restrict__ xin,
                                               const float* __restrict__ w1,
                                               const float* __restrict__ b1,
                                               __hip_bfloat16* __restrict__ h1, int b0){
  __shared__ float2 tin[18][19];
  __shared__ float wts[64*18];
  __shared__ float bia[64];
  int bg = blockIdx.z; int b = b0 + bg;
  int bx = blockIdx.x*16, by = blockIdx.y*16;
  int tid = threadIdx.x;
  for (int i = tid; i < 64*18; i += 256) wts[i] = w1[i];
  if (tid < 64) bia[tid] = b1[tid];
  for (int i = tid; i < 18*18; i += 256){
    int iy = i/18, ix = i%18; int gy = by+iy-1, gx = bx+ix-1;
    float2 t = make_float2(0.f, 0.f);
    if (gy>=0 && gy<NH && gx>=0 && gx<NW) t = xin[((size_t)b*NH + gy)*NW + gx];
    tin[iy][ix] = t;
  }
  __syncthreads();
  int px = tid & 15, py = tid >> 4;
  float acc[64];
  #pragma unroll
  for (int o=0;o<64;o++) acc[o] = bia[o];
  #pragma unroll
  for (int dy=0;dy<3;dy++)
  #pragma unroll
  for (int dx=0;dx<3;dx++){
    float2 iv = tin[py+dy][px+dx];
    int tap = dy*3+dx;
    #pragma unroll
    for (int o=0;o<64;o++)
      acc[o] += iv.x * wts[o*18 + tap] + iv.y * wts[o*18 + 9 + tap];
  }
  int gy = by+py, gx = bx+px;
  #pragma unroll
  for (int o=0;o<64;o++){
    float r = fmaxf(acc[o], 0.f);
    h1[(((size_t)bg*64 + o)*NH + gy)*NW + gx] = __float2bfloat16(r);
  }
}

__global__ __launch_bounds__(256) void k_conv2(const __hip_bfloat16* __restrict__ h1,
                                               const float* __restrict__ w2,
                                               const float* __restrict__ b2,
                                               __hip_bfloat16* __restrict__ h2){
  __shared__ float tin[8][18][19];
  __shared__ float wch[64*72];
  int bg = blockIdx.z;
  int bx = blockIdx.x*16, by = blockIdx.y*16;
  int tid = threadIdx.x; int lane = tid & 63; int ocg = tid >> 6;
  int px = lane & 7, py = lane >> 3;
  float acc[4][16];
  #pragma unroll
  for (int q=0;q<4;q++)
    #pragma unroll
    for (int o=0;o<16;o++) acc[q][o] = 0.f;
  for (int ch = 0; ch < 8; ch++){
    int ic0 = ch*8;
    for (int i = tid; i < 8*18*18; i += 256){
      int ic = i / 324; int rem = i % 324; int iy = rem/18, ix = rem%18;
      int gy = by+iy-1, gx = bx+ix-1;
      float t = 0.f;
      if (gy>=0 && gy<NH && gx>=0 && gx<NW)
        t = __bfloat162float(h1[(((size_t)bg*64 + ic0+ic)*NH + gy)*NW + gx]);
      tin[ic][iy][ix] = t;
    }
    for (int i = tid; i < 64*72; i += 256){
      int o = i / 72; int r = i % 72;
      wch[i] = w2[((size_t)o*64 + ic0 + r/9)*9 + (r%9)];
    }
    __syncthreads();
    #pragma unroll
    for (int ic=0; ic<8; ic++){
      #pragma unroll
      for (int dy=0;dy<3;dy++)
      #pragma unroll
      for (int dx=0;dx<3;dx++){
        float i00 = tin[ic][py+dy][px+dx];
        float i01 = tin[ic][py+dy][px+dx+8];
        float i10 = tin[ic][py+8+dy][px+dx];
        float i11 = tin[ic][py+8+dy][px+dx+8];
        int wbase = (ocg*16)*72 + ic*9 + dy*3 + dx;
        #pragma unroll
        for (int o=0;o<16;o++){
          float wv = wch[wbase + o*72];     // wave-uniform broadcast
          acc[0][o] += i00*wv; acc[1][o] += i01*wv;
          acc[2][o] += i10*wv; acc[3][o] += i11*wv;
        }
      }
    }
    __syncthreads();
  }
  #pragma unroll
  for (int o=0;o<16;o++){
    int oc = ocg*16 + o;
    float bv = b2[oc];
    #pragma unroll
    for (int q=0;q<4;q++){
      int gy = by + py + (q>>1)*8; int gx = bx + px + (q&1)*8;
      float r = fmaxf(acc[q][o] + bv, 0.f);
      h2[(((size_t)bg*64 + oc)*NH + gy)*NW + gx] = __float2bfloat16(r);
    }
  }
}

// reads h2 (group-local), xadj/x (global batch), writes rhs in-place over xadj
__global__ __launch_bounds__(256) void k_conv3(const __hip_bfloat16* __restrict__ h2,
                                               const float* __restrict__ w3,
                                               const float* __restrict__ b3,
                                               float2* __restrict__ xr,
                                               const float2* __restrict__ xin, int b0){
  __shared__ float tin[8][18][19];
  __shared__ float w3s[2*64*9];
  int bg = blockIdx.z; int b = b0 + bg;
  int bx = blockIdx.x*16, by = blockIdx.y*16;
  int tid = threadIdx.x;
  for (int i = tid; i < 2*64*9; i += 256) w3s[i] = w3[i];
  int px = tid & 15, py = tid >> 4;
  float acc0 = 0.f, acc1 = 0.f;
  for (int ch = 0; ch < 8; ch++){
    int ic0 = ch*8;
    __syncthreads();
    for (int i = tid; i < 8*18*18; i += 256){
      int ic = i / 324; int rem = i % 324; int iy = rem/18, ix = rem%18;
      int gy = by+iy-1, gx = bx+ix-1;
      float t = 0.f;
      if (gy>=0 && gy<NH && gx>=0 && gx<NW)
        t = __bfloat162float(h2[(((size_t)bg*64 + ic0+ic)*NH + gy)*NW + gx]);
      tin[ic][iy][ix] = t;
    }
    __syncthreads();
    #pragma unroll
    for (int ic=0; ic<8; ic++){
      #pragma unroll
      for (int dy=0;dy<3;dy++)
      #pragma unroll
      for (int dx=0;dx<3;dx++){
        float iv = tin[ic][py+dy][px+dx];
        int ictap = (ic0+ic)*9 + dy*3 + dx;
        acc0 += iv * w3s[ictap];
        acc1 += iv * w3s[576 + ictap];
      }
    }
  }
  int gy = by+py, gx = bx+px;
  size_t g = ((size_t)b*NH + gy)*NW + gx;
  float2 xa = xr[g]; float2 xv = xin[g];
  float2 o;
  o.x = xa.x + L2LAMF * (xv.x + acc0 + b3[0]);
  o.y = xa.y + L2LAMF * (xv.y + acc1 + b3[1]);
  xr[g] = o;
}

// ---------- CG glue ----------
__global__ __launch_bounds__(256) void k_cginit(const float2* __restrict__ rhs,
                                                const float2* __restrict__ Ax0,
                                                const float2* __restrict__ x0,
                                                float2* __restrict__ x,
                                                float2* __restrict__ r,
                                                float2* __restrict__ p,
                                                float* __restrict__ rs){
  __shared__ float red[4];
  int tid = threadIdx.x;
  int b = blockIdx.x / 400; int e = (blockIdx.x % 400)*256 + tid;
  size_t g = (size_t)b*NH*NW + e;
  float2 rh = rhs[g], ax = Ax0[g];
  float2 rv = make_float2(rh.x - ax.x, rh.y - ax.y);
  r[g] = rv; p[g] = rv; x[g] = x0[g];
  float partial = rv.x*rv.x + rv.y*rv.y;
  int lane = tid & 63, wid = tid >> 6;
  #pragma unroll
  for (int o=32;o>0;o>>=1) partial += __shfl_down(partial, o, 64);
  if (lane == 0) red[wid] = partial;
  __syncthreads();
  if (tid == 0) atomicAdd(&rs[b], red[0]+red[1]+red[2]+red[3]);
}

__global__ __launch_bounds__(256) void k_cgupdate(float2* __restrict__ x,
                                                  float2* __restrict__ r,
                                                  const float2* __restrict__ p,
                                                  const float2* __restrict__ Ap,
                                                  const float* __restrict__ rs_old,
                                                  const float* __restrict__ pAp,
                                                  float* __restrict__ rs_new){
  __shared__ float red[4];
  int tid = threadIdx.x;
  int b = blockIdx.x / 400; int e = (blockIdx.x % 400)*256 + tid;
  size_t g = (size_t)b*NH*NW + e;
  float alpha = rs_old[b] / pAp[b];
  float2 xv = x[g], pv = p[g], rv = r[g], av = Ap[g];
  xv.x += alpha*pv.x; xv.y += alpha*pv.y;
  rv.x -= alpha*av.x; rv.y -= alpha*av.y;
  x[g] = xv; r[g] = rv;
  float partial = rv.x*rv.x + rv.y*rv.y;
  int lane = tid & 63, wid = tid >> 6;
  #pragma unroll
  for (int o=32;o>0;o>>=1) partial += __shfl_down(partial, o, 64);
  if (lane == 0) red[wid] = partial;
  __syncthreads();
  if (tid == 0) atomicAdd(&rs_new[b], red[0]+red[1]+red[2]+red[3]);
}

__global__ __launch_bounds__(256) void k_cgp(float2* __restrict__ p,
                                             const float2* __restrict__ r,
                                             const float* __restrict__ rs_new,
                                             const float* __restrict__ rs_old){
  int tid = threadIdx.x;
  int b = blockIdx.x / 400; int e = (blockIdx.x % 400)*256 + tid;
  size_t g = (size_t)b*NH*NW + e;
  float beta = rs_new[b] / rs_old[b];
  float2 rv = r[g], pv = p[g];
  p[g] = make_float2(rv.x + beta*pv.x, rv.y + beta*pv.y);
}

extern "C" void kernel_launch(void* const* d_in, const int* in_sizes, int n_in,
                              void* d_out, int out_size, void* d_ws, size_t ws_size,
                              hipStream_t stream) {
  (void)in_sizes; (void)n_in; (void)out_size;
  const float2* x_in = (const float2*)d_in[0];
  const float2* maps = (const float2*)d_in[1];
  const float*  masks= (const float*)d_in[2];
  const float2* ksp  = (const float2*)d_in[3];
  const float* w1 = (const float*)d_in[4]; const float* b1 = (const float*)d_in[5];
  const float* w2 = (const float*)d_in[6]; const float* b2 = (const float*)d_in[7];
  const float* w3 = (const float*)d_in[8]; const float* b3 = (const float*)d_in[9];
  float2* xout = (float2*)d_out;

  const size_t VECB = (size_t)NB*NH*NW*sizeof(float2);          // 6.55 MB
  const size_t PERB = (size_t)NC*NH*NW*sizeof(float2);          // 9.83 MB (K per batch)
  const size_t HBUF = (size_t)64*NH*NW*sizeof(__hip_bfloat16);  // 13.1 MB (h per batch)
  auto rnd = [](size_t x){ return (x + 255) & ~(size_t)255; };
  size_t fixed = 4*rnd(VECB) + rnd(4096);
  int G = 8;     // batches per FFT-chain pass
  while (G > 1 && fixed + rnd((size_t)G*PERB) > ws_size) G >>= 1;
  int DEN_G = 8; // batches per denoiser pass (h1+h2 alias the K region)
  while (DEN_G > 1 &&
         fixed + rnd((size_t)G*PERB > (size_t)DEN_G*2*HBUF ? (size_t)G*PERB
                                                           : (size_t)DEN_G*2*HBUF) > ws_size)
    DEN_G >>= 1;
  size_t region = (size_t)G*PERB;
  if ((size_t)DEN_G*2*HBUF > region) region = (size_t)DEN_G*2*HBUF;

  char* ws = (char*)d_ws;
  size_t off = 0;
  auto alloc = [&](size_t bytes)->void*{ void* p = ws + off; off += rnd(bytes); return p; };
  float2* xr   = (float2*)alloc(VECB);   // xadj -> rhs (in-place)
  float2* Ap   = (float2*)alloc(VECB);
  float2* rbuf = (float2*)alloc(VECB);
  float2* pbuf = (float2*)alloc(VECB);
  float*  scal = (float*)alloc(4096);    // rs[i*8+b]; pAp at +64
  void*   shrd = alloc(region);          // K during FFT phases; h1/h2 during denoise
  float2* K = (float2*)shrd;
  __hip_bfloat16* h1 = (__hip_bfloat16*)shrd;
  __hip_bfloat16* h2 = h1 + (size_t)DEN_G*64*NH*NW;
  hipMemsetAsync(scal, 0, 4096, stream);

  const int gCol = G*NC*40;
  const int gRow = G*NC*NH/8;
  const int gIC  = G*NH;

  // adjoint: xadj -> xr  (uses K)
  for (int b0 = 0; b0 < NB; b0 += G){
    k_adjCol<<<gCol, 512, 0, stream>>>(ksp, masks, K, b0);
    k_rowIC<false><<<gIC, 256, 0, stream>>>(K, maps, nullptr, xr, nullptr, b0);
  }
  // denoiser: xr = xadj + lam*(x + CNN(x))  (K dead; region holds h1/h2)
  for (int b0 = 0; b0 < NB; b0 += DEN_G){
    dim3 gconv(20,20,DEN_G);
    k_conv1<<<gconv, 256, 0, stream>>>(x_in, w1, b1, h1, b0);
    k_conv2<<<gconv, 256, 0, stream>>>(h1, w2, b2, h2);
    k_conv3<<<gconv, 256, 0, stream>>>(h2, w3, b3, xr, x_in, b0);
  }
  // Aop(x0) -> Ap
  for (int b0 = 0; b0 < NB; b0 += G){
    k_rowF<<<gRow, 512, 0, stream>>>(x_in, maps, K, b0);
    k_colFMI<<<gCol, 512, 0, stream>>>(K, masks, b0);
    k_rowIC<true><<<gIC, 256, 0, stream>>>(K, maps, x_in, Ap, scal + 64, b0);
  }
  // r = rhs - Ax0; p = r; x = x0; rs0
  k_cginit<<<3200, 256, 0, stream>>>(xr, Ap, x_in, xout, rbuf, pbuf, scal);
  // 6 CG iterations
  for (int i = 1; i <= 6; i++){
    for (int b0 = 0; b0 < NB; b0 += G){
      k_rowF<<<gRow, 512, 0, stream>>>(pbuf, maps, K, b0);
      k_colFMI<<<gCol, 512, 0, stream>>>(K, masks, b0);
      k_rowIC<true><<<gIC, 256, 0, stream>>>(K, maps, pbuf, Ap, scal + 64 + i*8, b0);
    }
    k_cgupdate<<<3200, 256, 0, stream>>>(xout, rbuf, pbuf, Ap,
                                         scal + (i-1)*8, scal + 64 + i*8, scal + i*8);
    if (i < 6)
      k_cgp<<<3200, 256, 0, stream>>>(pbuf, rbuf, scal + i*8, scal + (i-1)*8);
  }
}

// Round 8
// 2451.604 us; speedup vs baseline: 10.7565x; 1.5989x over previous
//
#include <hip/hip_runtime.h>
#include <hip/hip_bf16.h>

#define NB 8
#define NC 12
#define NH 320
#define NW 320
#define L2LAMF 0.05f
#define SCALE_NORMAL (1.0f/(320.0f*320.0f))
#define SCALE_ADJ (1.0f/320.0f)

typedef __attribute__((ext_vector_type(8))) short bf16x8;
typedef __attribute__((ext_vector_type(4))) float f32x4;

__device__ __forceinline__ float2 cmulf(float2 a, float2 b){
  return make_float2(a.x*b.x - a.y*b.y, a.x*b.y + a.y*b.x);
}
__device__ __forceinline__ unsigned short f2bf(float f){
  __hip_bfloat16 h = __float2bfloat16(f);
  return *reinterpret_cast<unsigned short*>(&h);
}
__device__ __forceinline__ float bfbits2f(short s){
  unsigned u = ((unsigned)(unsigned short)s) << 16;
  return __uint_as_float(u);
}

// 320-point FFT: radix-5 in regs + 64-point DIF across the wave's lanes.
// Input: v[j] = x[lane + 64*j]. Output: v[k1] holds X[k1 + 5*brev6(lane)].
template<int S>
__device__ __forceinline__ void fft320(float2 v[5], int lane){
  const float PI = 3.14159265358979323846f;
  const float C1 = 0.30901699437494742f, S1 = 0.95105651629515357f;
  const float C2 = -0.80901699437494745f, S2 = 0.58778525229247314f;
  const float2 w5[5] = { make_float2(1.f,0.f), make_float2(C1, S*S1),
                         make_float2(C2, S*S2), make_float2(C2, -S*S2),
                         make_float2(C1, -S*S1) };
  float2 y[5];
  #pragma unroll
  for (int k=0;k<5;k++){
    float2 s = v[0];
    #pragma unroll
    for (int n=1;n<5;n++){
      float2 t = cmulf(v[n], w5[(n*k)%5]);
      s.x += t.x; s.y += t.y;
    }
    y[k] = s;
  }
  float ang = (float)S * (2.f*PI) * (float)lane * (1.f/320.f);
  float sn, cs; __sincosf(ang, &sn, &cs);
  float2 wt = make_float2(cs, sn);
  float2 t2 = wt;
  y[1] = cmulf(y[1], t2);
  t2 = cmulf(t2, wt); y[2] = cmulf(y[2], t2);
  t2 = cmulf(t2, wt); y[3] = cmulf(y[3], t2);
  t2 = cmulf(t2, wt); y[4] = cmulf(y[4], t2);
  #pragma unroll
  for (int h=32; h>=1; h>>=1){
    int j = lane & (h-1);
    bool up = (lane & h) != 0;
    float a2 = (float)S * PI * (float)j / (float)h;
    float ws, wc; __sincosf(a2, &ws, &wc);
    float2 w = make_float2(wc, ws);
    #pragma unroll
    for (int q=0;q<5;q++){
      float2 a = y[q];
      float2 b;
      b.x = __shfl_xor(a.x, h, 64);
      b.y = __shfl_xor(a.y, h, 64);
      float2 sum = make_float2(a.x+b.x, a.y+b.y);
      float2 dif = make_float2(b.x-a.x, b.y-a.y);
      float2 rot = cmulf(dif, w);
      y[q] = up ? rot : sum;
    }
  }
  #pragma unroll
  for (int q=0;q<5;q++) v[q] = y[q];
}

// ---------- coil-mult + (-1)^{h+w} + forward row FFT ----------
__global__ __launch_bounds__(512) void k_rowF(const float2* __restrict__ xin,
                                              const float2* __restrict__ maps,
                                              float2* __restrict__ K, int b0){
  __shared__ float2 lds[8][321];
  int tid = threadIdx.x; int wid = tid >> 6; int lane = tid & 63;
  int row = blockIdx.x * 8 + wid;
  int h = row % NH; int bc = row / NH; int c = bc % NC; int bg = bc / NC;
  int b = b0 + bg;
  const float2* xr = xin + ((size_t)b*NH + h)*NW;
  const float2* mr = maps + (((size_t)b*NC + c)*NH + h)*NW;
  float2 v[5];
  #pragma unroll
  for (int j=0;j<5;j++){
    int n = lane + 64*j;
    float2 t = cmulf(mr[n], xr[n]);
    float sg = ((h + n) & 1) ? -1.f : 1.f;
    v[j] = make_float2(t.x*sg, t.y*sg);
  }
  fft320<-1>(v, lane);
  int br = __brev((unsigned)lane) >> 26;
  #pragma unroll
  for (int k1=0;k1<5;k1++) lds[wid][k1 + 5*br] = v[k1];
  float2* Kr = K + (((size_t)(bg*NC + c))*NH + h)*NW;
  #pragma unroll
  for (int j=0;j<5;j++){ int n = lane + 64*j; Kr[n] = lds[wid][n]; }
}

// ---------- column FFT -> mask*scale -> column IFFT (in place) ----------
__global__ __launch_bounds__(512) void k_colFMI(float2* __restrict__ K,
                                                const float* __restrict__ masks, int b0){
  __shared__ float2 tile[8][321];
  int tid = threadIdx.x;
  int bid = blockIdx.x;
  int ct = bid % 40; int c = (bid/40) % NC; int bg = bid/(40*NC);
  int b = b0 + bg;
  int col0 = ct * 8;
  float2* base = K + ((size_t)(bg*NC + c))*NH*NW;
  #pragma unroll
  for (int it=0; it<5; it++){
    int e = tid + 512*it; int hh = e >> 3; int ci = e & 7;
    tile[ci][hh] = base[(size_t)hh*NW + col0 + ci];
  }
  __syncthreads();
  int wid = tid >> 6, lane = tid & 63;
  int col = col0 + wid;
  float2 v[5];
  #pragma unroll
  for (int j=0;j<5;j++) v[j] = tile[wid][lane + 64*j];
  fft320<-1>(v, lane);
  int br = __brev((unsigned)lane) >> 26;
  const float* mb = masks + (size_t)b*NH*NW + col;
  #pragma unroll
  for (int k1=0;k1<5;k1++){
    int kh = k1 + 5*br;
    float mv = mb[(size_t)kh*NW] * SCALE_NORMAL;
    v[k1].x *= mv; v[k1].y *= mv;
    tile[wid][kh] = v[k1];
  }
  #pragma unroll
  for (int j=0;j<5;j++) v[j] = tile[wid][lane + 64*j];
  fft320<1>(v, lane);
  #pragma unroll
  for (int k1=0;k1<5;k1++) tile[wid][k1 + 5*br] = v[k1];
  __syncthreads();
  #pragma unroll
  for (int it=0; it<5; it++){
    int e = tid + 512*it; int hh = e >> 3; int ci = e & 7;
    base[(size_t)hh*NW + col0 + ci] = tile[ci][hh];
  }
}

// ---------- adjoint column: (-1)^{kh+kw}*mask*(1/320) then column IFFT ----------
__global__ __launch_bounds__(512) void k_adjCol(const float2* __restrict__ ksp,
                                                const float* __restrict__ masks,
                                                float2* __restrict__ K, int b0){
  __shared__ float2 tile[8][321];
  int tid = threadIdx.x;
  int bid = blockIdx.x;
  int ct = bid % 40; int c = (bid/40) % NC; int bg = bid/(40*NC);
  int b = b0 + bg;
  int col0 = ct * 8;
  const float2* src = ksp + ((size_t)(b*NC + c))*NH*NW;
  float2* dst = K + ((size_t)(bg*NC + c))*NH*NW;
  #pragma unroll
  for (int it=0; it<5; it++){
    int e = tid + 512*it; int hh = e >> 3; int ci = e & 7;
    tile[ci][hh] = src[(size_t)hh*NW + col0 + ci];
  }
  __syncthreads();
  int wid = tid >> 6, lane = tid & 63;
  int col = col0 + wid;
  const float* mb = masks + (size_t)b*NH*NW + col;
  float2 v[5];
  #pragma unroll
  for (int j=0;j<5;j++){
    int hh = lane + 64*j;
    float2 t = tile[wid][hh];
    float mv = mb[(size_t)hh*NW] * (((hh + col) & 1) ? -SCALE_ADJ : SCALE_ADJ);
    v[j] = make_float2(t.x*mv, t.y*mv);
  }
  fft320<1>(v, lane);
  int br = __brev((unsigned)lane) >> 26;
  #pragma unroll
  for (int k1=0;k1<5;k1++) tile[wid][k1 + 5*br] = v[k1];
  __syncthreads();
  #pragma unroll
  for (int it=0; it<5; it++){
    int e = tid + 512*it; int hh = e >> 3; int ci = e & 7;
    dst[(size_t)hh*NW + col0 + ci] = tile[ci][hh];
  }
}

// ---------- row IFFT + (-1)^{h+w} + conj(maps) combine (+ lam*p, pAp) ----------
template<bool AOP>
__global__ __launch_bounds__(256) void k_rowIC(const float2* __restrict__ K,
                                               const float2* __restrict__ maps,
                                               const float2* __restrict__ p,
                                               float2* __restrict__ out,
                                               float* __restrict__ pAp, int b0){
  __shared__ float2 acc_lds[4][321];
  __shared__ float red[4];
  int tid = threadIdx.x; int wid = tid >> 6; int lane = tid & 63;
  int bg = blockIdx.x / NH; int h = blockIdx.x % NH;
  int b = b0 + bg;
  int br = __brev((unsigned)lane) >> 26;
  float2 acc[5];
  #pragma unroll
  for (int k1=0;k1<5;k1++) acc[k1] = make_float2(0.f, 0.f);
  for (int c = wid; c < NC; c += 4){
    const float2* Kr = K + (((size_t)(bg*NC + c))*NH + h)*NW;
    float2 v[5];
    #pragma unroll
    for (int j=0;j<5;j++) v[j] = Kr[lane + 64*j];
    fft320<1>(v, lane);
    const float2* mr = maps + (((size_t)b*NC + c)*NH + h)*NW;
    #pragma unroll
    for (int k1=0;k1<5;k1++){
      int n = k1 + 5*br;
      float2 m = mr[n];
      float2 t = make_float2(m.x*v[k1].x + m.y*v[k1].y, m.x*v[k1].y - m.y*v[k1].x);
      float sg = ((h + n) & 1) ? -1.f : 1.f;
      acc[k1].x += t.x*sg; acc[k1].y += t.y*sg;
    }
  }
  #pragma unroll
  for (int k1=0;k1<5;k1++) acc_lds[wid][k1 + 5*br] = acc[k1];
  __syncthreads();
  float partial = 0.f;
  const float2* prow = AOP ? (p + ((size_t)b*NH + h)*NW) : (const float2*)nullptr;
  float2* orow = out + ((size_t)b*NH + h)*NW;
  for (int n = tid; n < NW; n += 256){
    float2 s;
    s.x = acc_lds[0][n].x + acc_lds[1][n].x + acc_lds[2][n].x + acc_lds[3][n].x;
    s.y = acc_lds[0][n].y + acc_lds[1][n].y + acc_lds[2][n].y + acc_lds[3][n].y;
    if (AOP){
      float2 pv = prow[n];
      s.x += L2LAMF * pv.x; s.y += L2LAMF * pv.y;
      partial += pv.x*s.x + pv.y*s.y;
    }
    orow[n] = s;
  }
  if (AOP){
    #pragma unroll
    for (int o=32;o>0;o>>=1) partial += __shfl_down(partial, o, 64);
    if (lane == 0) red[wid] = partial;
    __syncthreads();
    if (tid == 0) atomicAdd(&pAp[b], red[0]+red[1]+red[2]+red[3]);
  }
}

// ---------- weight prepack: w2 [oc][ic][3][3] fp32 -> wpk [tap][oc][ic] bf16 ----------
__global__ __launch_bounds__(256) void k_prepw2(const float* __restrict__ w2,
                                                __hip_bfloat16* __restrict__ wpk){
  int i = blockIdx.x*256 + threadIdx.x;
  if (i < 9*64*64){
    int t = i / 4096; int rem = i & 4095; int oc = rem >> 6; int ic = rem & 63;
    wpk[i] = __float2bfloat16(w2[oc*576 + ic*9 + t]);
  }
}

// ---------- conv1: 2->64, writes h1 channel-last [y][x][ic] bf16 ----------
__global__ __launch_bounds__(256) void k_conv1(const float2* __restrict__ xin,
                                               const float* __restrict__ w1,
                                               const float* __restrict__ b1,
                                               __hip_bfloat16* __restrict__ h1, int b0){
  __shared__ float2 tin[18][19];
  __shared__ float wts[64*18];
  __shared__ float bia[64];
  int bg = blockIdx.z; int b = b0 + bg;
  int bx = blockIdx.x*16, by = blockIdx.y*16;
  int tid = threadIdx.x;
  for (int i = tid; i < 64*18; i += 256) wts[i] = w1[i];
  if (tid < 64) bia[tid] = b1[tid];
  for (int i = tid; i < 18*18; i += 256){
    int iy = i/18, ix = i%18; int gy = by+iy-1, gx = bx+ix-1;
    float2 t = make_float2(0.f, 0.f);
    if (gy>=0 && gy<NH && gx>=0 && gx<NW) t = xin[((size_t)b*NH + gy)*NW + gx];
    tin[iy][ix] = t;
  }
  __syncthreads();
  int px = tid & 15, py = tid >> 4;
  float acc[64];
  #pragma unroll
  for (int o=0;o<64;o++) acc[o] = bia[o];
  #pragma unroll
  for (int dy=0;dy<3;dy++)
  #pragma unroll
  for (int dx=0;dx<3;dx++){
    float2 iv = tin[py+dy][px+dx];
    int tap = dy*3+dx;
    #pragma unroll
    for (int o=0;o<64;o++)
      acc[o] += iv.x * wts[o*18 + tap] + iv.y * wts[o*18 + 9 + tap];
  }
  int gy = by+py, gx = bx+px;
  size_t base = (((size_t)bg*NH + gy)*NW + gx)*64;
  #pragma unroll
  for (int o4=0;o4<16;o4++){
    ushort4 pk;
    pk.x = f2bf(fmaxf(acc[o4*4+0], 0.f));
    pk.y = f2bf(fmaxf(acc[o4*4+1], 0.f));
    pk.z = f2bf(fmaxf(acc[o4*4+2], 0.f));
    pk.w = f2bf(fmaxf(acc[o4*4+3], 0.f));
    *(ushort4*)(h1 + base + o4*4) = pk;
  }
}

// ---------- conv2 (MFMA implicit GEMM): 64->64, h1/h2 channel-last bf16 ----------
// Block: 8x8 px x 64 oc. 4 waves: wave w -> oc [16w,16w+16). K = 9 taps x 64 ic.
__global__ __launch_bounds__(256) void k_conv2(const __hip_bfloat16* __restrict__ h1,
                                               const __hip_bfloat16* __restrict__ wpk,
                                               const float* __restrict__ b2,
                                               __hip_bfloat16* __restrict__ h2){
  __shared__ __align__(16) short tile[100][64];   // [sp][ic], ic-blk ^ (sp&7)
  __shared__ __align__(16) short wlds[3][64][64]; // [t][oc][ic], ic-blk ^ (oc&7)
  int tid = threadIdx.x; int lane = tid & 63; int wid = tid >> 6;
  int bg = blockIdx.z;
  int x0 = blockIdx.x*8, y0 = blockIdx.y*8;
  // stage input tile (10x10 halo), zero-pad OOB
  for (int i = tid; i < 800; i += 256){
    int sp = i >> 3, blk = i & 7;
    int yy = sp / 10, xx = sp % 10;
    int gy = y0 + yy - 1, gx = x0 + xx - 1;
    uint4 val = make_uint4(0u,0u,0u,0u);
    if (gy>=0 && gy<NH && gx>=0 && gx<NW)
      val = *(const uint4*)(h1 + (((size_t)bg*NH + gy)*NW + gx)*64 + blk*8);
    *(uint4*)&tile[sp][(blk ^ (sp & 7))*8] = val;
  }
  f32x4 acc[4];
  #pragma unroll
  for (int n=0;n<4;n++) acc[n] = (f32x4){0.f,0.f,0.f,0.f};
  #pragma unroll
  for (int c = 0; c < 3; c++){
    __syncthreads();
    for (int i = tid; i < 1536; i += 256){
      int t = i >> 9; int rem = i & 511; int oc = rem >> 3; int blk = rem & 7;
      uint4 val = *(const uint4*)(wpk + (size_t)(3*c + t)*4096 + oc*64 + blk*8);
      *(uint4*)&wlds[t][oc][(blk ^ (oc & 7))*8] = val;
    }
    __syncthreads();
    #pragma unroll
    for (int t=0;t<3;t++){
      int tap = 3*c + t;
      int dy = tap / 3, dx = tap % 3;
      #pragma unroll
      for (int kh=0; kh<2; kh++){
        int icblk = kh*4 + (lane >> 4);
        int oc = wid*16 + (lane & 15);
        bf16x8 afr = *(bf16x8*)&wlds[t][oc][(icblk ^ (oc & 7))*8];
        #pragma unroll
        for (int n=0;n<4;n++){
          int px = n*16 + (lane & 15);
          int sp = ((px >> 3) + dy)*10 + (px & 7) + dx;
          bf16x8 bfr = *(bf16x8*)&tile[sp][(icblk ^ (sp & 7))*8];
          acc[n] = __builtin_amdgcn_mfma_f32_16x16x32_bf16(afr, bfr, acc[n], 0, 0, 0);
        }
      }
    }
  }
  // epilogue: D col=lane&15 -> px, row=(lane>>4)*4+reg -> oc
  int oc0 = wid*16 + (lane >> 4)*4;
  float b4[4];
  #pragma unroll
  for (int r=0;r<4;r++) b4[r] = b2[oc0 + r];
  #pragma unroll
  for (int n=0;n<4;n++){
    int px = n*16 + (lane & 15);
    int gy = y0 + (px >> 3), gx = x0 + (px & 7);
    ushort4 pk;
    pk.x = f2bf(fmaxf(acc[n][0] + b4[0], 0.f));
    pk.y = f2bf(fmaxf(acc[n][1] + b4[1], 0.f));
    pk.z = f2bf(fmaxf(acc[n][2] + b4[2], 0.f));
    pk.w = f2bf(fmaxf(acc[n][3] + b4[3], 0.f));
    *(ushort4*)(h2 + (((size_t)bg*NH + gy)*NW + gx)*64 + oc0) = pk;
  }
}

// ---------- conv3: 64->2, reads h2 channel-last; rhs in-place over xadj ----------
__global__ __launch_bounds__(256) void k_conv3(const __hip_bfloat16* __restrict__ h2,
                                               const float* __restrict__ w3,
                                               const float* __restrict__ b3,
                                               float2* __restrict__ xr,
                                               const float2* __restrict__ xin, int b0){
  __shared__ __align__(16) short tile[324][64];  // [sp][ic], ic-blk ^ (sp&7)
  __shared__ float w3s[2][576];
  int tid = threadIdx.x;
  int bg = blockIdx.z; int b = b0 + bg;
  int x0 = blockIdx.x*16, y0 = blockIdx.y*16;
  for (int i = tid; i < 1152; i += 256) w3s[i/576][i%576] = w3[i];
  for (int i = tid; i < 2592; i += 256){
    int sp = i >> 3, blk = i & 7;
    int yy = sp / 18, xx = sp % 18;
    int gy = y0 + yy - 1, gx = x0 + xx - 1;
    uint4 val = make_uint4(0u,0u,0u,0u);
    if (gy>=0 && gy<NH && gx>=0 && gx<NW)
      val = *(const uint4*)(h2 + (((size_t)bg*NH + gy)*NW + gx)*64 + blk*8);
    *(uint4*)&tile[sp][(blk ^ (sp & 7))*8] = val;
  }
  __syncthreads();
  int px = tid & 15, py = tid >> 4;
  float a0 = 0.f, a1 = 0.f;
  #pragma unroll
  for (int dy=0;dy<3;dy++)
  #pragma unroll
  for (int dx=0;dx<3;dx++){
    int sp = (py+dy)*18 + px + dx;
    int tap = dy*3 + dx;
    #pragma unroll
    for (int blk=0;blk<8;blk++){
      bf16x8 v8 = *(bf16x8*)&tile[sp][(blk ^ (sp & 7))*8];
      #pragma unroll
      for (int j=0;j<8;j++){
        float v = bfbits2f(v8[j]);
        int ic = blk*8 + j;
        a0 += v * w3s[0][ic*9 + tap];
        a1 += v * w3s[1][ic*9 + tap];
      }
    }
  }
  int gy = y0 + py, gx = x0 + px;
  size_t g = ((size_t)b*NH + gy)*NW + gx;
  float2 xa = xr[g]; float2 xv = xin[g];
  float2 o;
  o.x = xa.x + L2LAMF * (xv.x + a0 + b3[0]);
  o.y = xa.y + L2LAMF * (xv.y + a1 + b3[1]);
  xr[g] = o;
}

// ---------- CG glue ----------
__global__ __launch_bounds__(256) void k_cginit(const float2* __restrict__ rhs,
                                                const float2* __restrict__ Ax0,
                                                const float2* __restrict__ x0,
                                                float2* __restrict__ x,
                                                float2* __restrict__ r,
                                                float2* __restrict__ p,
                                                float* __restrict__ rs){
  __shared__ float red[4];
  int tid = threadIdx.x;
  int b = blockIdx.x / 400; int e = (blockIdx.x % 400)*256 + tid;
  size_t g = (size_t)b*NH*NW + e;
  float2 rh = rhs[g], ax = Ax0[g];
  float2 rv = make_float2(rh.x - ax.x, rh.y - ax.y);
  r[g] = rv; p[g] = rv; x[g] = x0[g];
  float partial = rv.x*rv.x + rv.y*rv.y;
  int lane = tid & 63, wid = tid >> 6;
  #pragma unroll
  for (int o=32;o>0;o>>=1) partial += __shfl_down(partial, o, 64);
  if (lane == 0) red[wid] = partial;
  __syncthreads();
  if (tid == 0) atomicAdd(&rs[b], red[0]+red[1]+red[2]+red[3]);
}

__global__ __launch_bounds__(256) void k_cgupdate(float2* __restrict__ x,
                                                  float2* __restrict__ r,
                                                  const float2* __restrict__ p,
                                                  const float2* __restrict__ Ap,
                                                  const float* __restrict__ rs_old,
                                                  const float* __restrict__ pAp,
                                                  float* __restrict__ rs_new){
  __shared__ float red[4];
  int tid = threadIdx.x;
  int b = blockIdx.x / 400; int e = (blockIdx.x % 400)*256 + tid;
  size_t g = (size_t)b*NH*NW + e;
  float alpha = rs_old[b] / pAp[b];
  float2 xv = x[g], pv = p[g], rv = r[g], av = Ap[g];
  xv.x += alpha*pv.x; xv.y += alpha*pv.y;
  rv.x -= alpha*av.x; rv.y -= alpha*av.y;
  x[g] = xv; r[g] = rv;
  float partial = rv.x*rv.x + rv.y*rv.y;
  int lane = tid & 63, wid = tid >> 6;
  #pragma unroll
  for (int o=32;o>0;o>>=1) partial += __shfl_down(partial, o, 64);
  if (lane == 0) red[wid] = partial;
  __syncthreads();
  if (tid == 0) atomicAdd(&rs_new[b], red[0]+red[1]+red[2]+red[3]);
}

__global__ __launch_bounds__(256) void k_cgp(float2* __restrict__ p,
                                             const float2* __restrict__ r,
                                             const float* __restrict__ rs_new,
                                             const float* __restrict__ rs_old){
  int tid = threadIdx.x;
  int b = blockIdx.x / 400; int e = (blockIdx.x % 400)*256 + tid;
  size_t g = (size_t)b*NH*NW + e;
  float beta = rs_new[b] / rs_old[b];
  float2 rv = r[g], pv = p[g];
  p[g] = make_float2(rv.x + beta*pv.x, rv.y + beta*pv.y);
}

extern "C" void kernel_launch(void* const* d_in, const int* in_sizes, int n_in,
                              void* d_out, int out_size, void* d_ws, size_t ws_size,
                              hipStream_t stream) {
  (void)in_sizes; (void)n_in; (void)out_size;
  const float2* x_in = (const float2*)d_in[0];
  const float2* maps = (const float2*)d_in[1];
  const float*  masks= (const float*)d_in[2];
  const float2* ksp  = (const float2*)d_in[3];
  const float* w1 = (const float*)d_in[4]; const float* b1 = (const float*)d_in[5];
  const float* w2 = (const float*)d_in[6]; const float* b2 = (const float*)d_in[7];
  const float* w3 = (const float*)d_in[8]; const float* b3 = (const float*)d_in[9];
  float2* xout = (float2*)d_out;

  const size_t VECB = (size_t)NB*NH*NW*sizeof(float2);          // 6.55 MB
  const size_t PERB = (size_t)NC*NH*NW*sizeof(float2);          // 9.83 MB (K per batch)
  const size_t HBUF = (size_t)64*NH*NW*sizeof(__hip_bfloat16);  // 13.1 MB (h per batch)
  const size_t WPKB = (size_t)9*64*64*sizeof(__hip_bfloat16);   // 73.7 KB
  auto rnd = [](size_t x){ return (x + 255) & ~(size_t)255; };
  size_t fixed = 4*rnd(VECB) + rnd(4096) + rnd(WPKB);
  int G = 8;
  while (G > 1 && fixed + rnd((size_t)G*PERB) > ws_size) G >>= 1;
  int DEN_G = 8;
  while (DEN_G > 1 &&
         fixed + rnd((size_t)G*PERB > (size_t)DEN_G*2*HBUF ? (size_t)G*PERB
                                                           : (size_t)DEN_G*2*HBUF) > ws_size)
    DEN_G >>= 1;
  size_t region = (size_t)G*PERB;
  if ((size_t)DEN_G*2*HBUF > region) region = (size_t)DEN_G*2*HBUF;

  char* ws = (char*)d_ws;
  size_t off = 0;
  auto alloc = [&](size_t bytes)->void*{ void* p = ws + off; off += rnd(bytes); return p; };
  float2* xr   = (float2*)alloc(VECB);   // xadj -> rhs (in-place)
  float2* Ap   = (float2*)alloc(VECB);
  float2* rbuf = (float2*)alloc(VECB);
  float2* pbuf = (float2*)alloc(VECB);
  float*  scal = (float*)alloc(4096);    // rs[i*8+b]; pAp at +64
  __hip_bfloat16* wpk = (__hip_bfloat16*)alloc(WPKB);
  void*   shrd = alloc(region);          // K during FFT phases; h1/h2 during denoise
  float2* K = (float2*)shrd;
  __hip_bfloat16* h1 = (__hip_bfloat16*)shrd;
  __hip_bfloat16* h2 = h1 + (size_t)DEN_G*64*NH*NW;
  hipMemsetAsync(scal, 0, 4096, stream);

  const int gCol = G*NC*40;
  const int gRow = G*NC*NH/8;
  const int gIC  = G*NH;

  // adjoint: xadj -> xr  (uses K)
  for (int b0 = 0; b0 < NB; b0 += G){
    k_adjCol<<<gCol, 512, 0, stream>>>(ksp, masks, K, b0);
    k_rowIC<false><<<gIC, 256, 0, stream>>>(K, maps, nullptr, xr, nullptr, b0);
  }
  // denoiser: xr = xadj + lam*(x + CNN(x))  (K dead; region holds h1/h2)
  k_prepw2<<<144, 256, 0, stream>>>(w2, wpk);
  for (int b0 = 0; b0 < NB; b0 += DEN_G){
    k_conv1<<<dim3(20,20,DEN_G), 256, 0, stream>>>(x_in, w1, b1, h1, b0);
    k_conv2<<<dim3(40,40,DEN_G), 256, 0, stream>>>(h1, wpk, b2, h2);
    k_conv3<<<dim3(20,20,DEN_G), 256, 0, stream>>>(h2, w3, b3, xr, x_in, b0);
  }
  // Aop(x0) -> Ap
  for (int b0 = 0; b0 < NB; b0 += G){
    k_rowF<<<gRow, 512, 0, stream>>>(x_in, maps, K, b0);
    k_colFMI<<<gCol, 512, 0, stream>>>(K, masks, b0);
    k_rowIC<true><<<gIC, 256, 0, stream>>>(K, maps, x_in, Ap, scal + 64, b0);
  }
  // r = rhs - Ax0; p = r; x = x0; rs0
  k_cginit<<<3200, 256, 0, stream>>>(xr, Ap, x_in, xout, rbuf, pbuf, scal);
  // 6 CG iterations
  for (int i = 1; i <= 6; i++){
    for (int b0 = 0; b0 < NB; b0 += G){
      k_rowF<<<gRow, 512, 0, stream>>>(pbuf, maps, K, b0);
      k_colFMI<<<gCol, 512, 0, stream>>>(K, masks, b0);
      k_rowIC<true><<<gIC, 256, 0, stream>>>(K, maps, pbuf, Ap, scal + 64 + i*8, b0);
    }
    k_cgupdate<<<3200, 256, 0, stream>>>(xout, rbuf, pbuf, Ap,
                                         scal + (i-1)*8, scal + 64 + i*8, scal + i*8);
    if (i < 6)
      k_cgp<<<3200, 256, 0, stream>>>(pbuf, rbuf, scal + i*8, scal + (i-1)*8);
  }
}

// Round 10
// 2280.423 us; speedup vs baseline: 11.5639x; 1.0751x over previous
//
#include <hip/hip_runtime.h>
#include <hip/hip_bf16.h>

#define NB 8
#define NC 12
#define NH 320
#define NW 320
#define L2LAMF 0.05f
#define SCALE_NORMAL (1.0f/(320.0f*320.0f))
#define SCALE_ADJ (1.0f/320.0f)

typedef __attribute__((ext_vector_type(8))) short bf16x8;
typedef __attribute__((ext_vector_type(4))) float f32x4;

__device__ __forceinline__ float2 cmulf(float2 a, float2 b){
  return make_float2(a.x*b.x - a.y*b.y, a.x*b.y + a.y*b.x);
}
__device__ __forceinline__ unsigned short f2bf(float f){
  __hip_bfloat16 h = __float2bfloat16(f);
  return *reinterpret_cast<unsigned short*>(&h);
}
__device__ __forceinline__ float bfbits2f(short s){
  unsigned u = ((unsigned)(unsigned short)s) << 16;
  return __uint_as_float(u);
}

// 320-point FFT: radix-5 in regs + 64-point DIF across the wave's lanes.
// Input: v[j] = x[lane + 64*j]. Output: v[k1] holds X[k1 + 5*brev6(lane)].
template<int S>
__device__ __forceinline__ void fft320(float2 v[5], int lane){
  const float PI = 3.14159265358979323846f;
  const float C1 = 0.30901699437494742f, S1 = 0.95105651629515357f;
  const float C2 = -0.80901699437494745f, S2 = 0.58778525229247314f;
  const float2 w5[5] = { make_float2(1.f,0.f), make_float2(C1, S*S1),
                         make_float2(C2, S*S2), make_float2(C2, -S*S2),
                         make_float2(C1, -S*S1) };
  float2 y[5];
  #pragma unroll
  for (int k=0;k<5;k++){
    float2 s = v[0];
    #pragma unroll
    for (int n=1;n<5;n++){
      float2 t = cmulf(v[n], w5[(n*k)%5]);
      s.x += t.x; s.y += t.y;
    }
    y[k] = s;
  }
  float ang = (float)S * (2.f*PI) * (float)lane * (1.f/320.f);
  float sn, cs; __sincosf(ang, &sn, &cs);
  float2 wt = make_float2(cs, sn);
  float2 t2 = wt;
  y[1] = cmulf(y[1], t2);
  t2 = cmulf(t2, wt); y[2] = cmulf(y[2], t2);
  t2 = cmulf(t2, wt); y[3] = cmulf(y[3], t2);
  t2 = cmulf(t2, wt); y[4] = cmulf(y[4], t2);
  #pragma unroll
  for (int h=32; h>=1; h>>=1){
    int j = lane & (h-1);
    bool up = (lane & h) != 0;
    float a2 = (float)S * PI * (float)j / (float)h;
    float ws, wc; __sincosf(a2, &ws, &wc);
    float2 w = make_float2(wc, ws);
    #pragma unroll
    for (int q=0;q<5;q++){
      float2 a = y[q];
      float2 b;
      b.x = __shfl_xor(a.x, h, 64);
      b.y = __shfl_xor(a.y, h, 64);
      float2 sum = make_float2(a.x+b.x, a.y+b.y);
      float2 dif = make_float2(b.x-a.x, b.y-a.y);
      float2 rot = cmulf(dif, w);
      y[q] = up ? rot : sum;
    }
  }
  #pragma unroll
  for (int q=0;q<5;q++) v[q] = y[q];
}

// ---------- coil-mult + (-1)^{h+w} + forward row FFT ----------
__global__ __launch_bounds__(512) void k_rowF(const float2* __restrict__ xin,
                                              const float2* __restrict__ maps,
                                              float2* __restrict__ K, int b0){
  __shared__ float2 lds[8][321];
  int tid = threadIdx.x; int wid = tid >> 6; int lane = tid & 63;
  int row = blockIdx.x * 8 + wid;
  int h = row % NH; int bc = row / NH; int c = bc % NC; int bg = bc / NC;
  int b = b0 + bg;
  const float2* xr = xin + ((size_t)b*NH + h)*NW;
  const float2* mr = maps + (((size_t)b*NC + c)*NH + h)*NW;
  float2 v[5];
  #pragma unroll
  for (int j=0;j<5;j++){
    int n = lane + 64*j;
    float2 t = cmulf(mr[n], xr[n]);
    float sg = ((h + n) & 1) ? -1.f : 1.f;
    v[j] = make_float2(t.x*sg, t.y*sg);
  }
  fft320<-1>(v, lane);
  int br = __brev((unsigned)lane) >> 26;
  #pragma unroll
  for (int k1=0;k1<5;k1++) lds[wid][k1 + 5*br] = v[k1];
  float2* Kr = K + (((size_t)(bg*NC + c))*NH + h)*NW;
  #pragma unroll
  for (int j=0;j<5;j++){ int n = lane + 64*j; Kr[n] = lds[wid][n]; }
}

// ---------- column FFT -> mask*scale -> column IFFT (in place) ----------
__global__ __launch_bounds__(512) void k_colFMI(float2* __restrict__ K,
                                                const float* __restrict__ masks, int b0){
  __shared__ float2 tile[8][321];
  int tid = threadIdx.x;
  int bid = blockIdx.x;
  int ct = bid % 40; int c = (bid/40) % NC; int bg = bid/(40*NC);
  int b = b0 + bg;
  int col0 = ct * 8;
  float2* base = K + ((size_t)(bg*NC + c))*NH*NW;
  #pragma unroll
  for (int it=0; it<5; it++){
    int e = tid + 512*it; int hh = e >> 3; int ci = e & 7;
    tile[ci][hh] = base[(size_t)hh*NW + col0 + ci];
  }
  __syncthreads();
  int wid = tid >> 6, lane = tid & 63;
  int col = col0 + wid;
  float2 v[5];
  #pragma unroll
  for (int j=0;j<5;j++) v[j] = tile[wid][lane + 64*j];
  fft320<-1>(v, lane);
  int br = __brev((unsigned)lane) >> 26;
  const float* mb = masks + (size_t)b*NH*NW + col;
  #pragma unroll
  for (int k1=0;k1<5;k1++){
    int kh = k1 + 5*br;
    float mv = mb[(size_t)kh*NW] * SCALE_NORMAL;
    v[k1].x *= mv; v[k1].y *= mv;
    tile[wid][kh] = v[k1];
  }
  #pragma unroll
  for (int j=0;j<5;j++) v[j] = tile[wid][lane + 64*j];
  fft320<1>(v, lane);
  #pragma unroll
  for (int k1=0;k1<5;k1++) tile[wid][k1 + 5*br] = v[k1];
  __syncthreads();
  #pragma unroll
  for (int it=0; it<5; it++){
    int e = tid + 512*it; int hh = e >> 3; int ci = e & 7;
    base[(size_t)hh*NW + col0 + ci] = tile[ci][hh];
  }
}

// ---------- adjoint column: (-1)^{kh+kw}*mask*(1/320) then column IFFT ----------
__global__ __launch_bounds__(512) void k_adjCol(const float2* __restrict__ ksp,
                                                const float* __restrict__ masks,
                                                float2* __restrict__ K, int b0){
  __shared__ float2 tile[8][321];
  int tid = threadIdx.x;
  int bid = blockIdx.x;
  int ct = bid % 40; int c = (bid/40) % NC; int bg = bid/(40*NC);
  int b = b0 + bg;
  int col0 = ct * 8;
  const float2* src = ksp + ((size_t)(b*NC + c))*NH*NW;
  float2* dst = K + ((size_t)(bg*NC + c))*NH*NW;
  #pragma unroll
  for (int it=0; it<5; it++){
    int e = tid + 512*it; int hh = e >> 3; int ci = e & 7;
    tile[ci][hh] = src[(size_t)hh*NW + col0 + ci];
  }
  __syncthreads();
  int wid = tid >> 6, lane = tid & 63;
  int col = col0 + wid;
  const float* mb = masks + (size_t)b*NH*NW + col;
  float2 v[5];
  #pragma unroll
  for (int j=0;j<5;j++){
    int hh = lane + 64*j;
    float2 t = tile[wid][hh];
    float mv = mb[(size_t)hh*NW] * (((hh + col) & 1) ? -SCALE_ADJ : SCALE_ADJ);
    v[j] = make_float2(t.x*mv, t.y*mv);
  }
  fft320<1>(v, lane);
  int br = __brev((unsigned)lane) >> 26;
  #pragma unroll
  for (int k1=0;k1<5;k1++) tile[wid][k1 + 5*br] = v[k1];
  __syncthreads();
  #pragma unroll
  for (int it=0; it<5; it++){
    int e = tid + 512*it; int hh = e >> 3; int ci = e & 7;
    dst[(size_t)hh*NW + col0 + ci] = tile[ci][hh];
  }
}

// ---------- row IFFT + (-1)^{h+w} + conj(maps) combine (+ lam*p, pAp) ----------
template<bool AOP>
__global__ __launch_bounds__(256) void k_rowIC(const float2* __restrict__ K,
                                               const float2* __restrict__ maps,
                                               const float2* __restrict__ p,
                                               float2* __restrict__ out,
                                               float* __restrict__ pAp, int b0){
  __shared__ float2 acc_lds[4][321];
  __shared__ float red[4];
  int tid = threadIdx.x; int wid = tid >> 6; int lane = tid & 63;
  int bg = blockIdx.x / NH; int h = blockIdx.x % NH;
  int b = b0 + bg;
  int br = __brev((unsigned)lane) >> 26;
  float2 acc[5];
  #pragma unroll
  for (int k1=0;k1<5;k1++) acc[k1] = make_float2(0.f, 0.f);
  for (int c = wid; c < NC; c += 4){
    const float2* Kr = K + (((size_t)(bg*NC + c))*NH + h)*NW;
    float2 v[5];
    #pragma unroll
    for (int j=0;j<5;j++) v[j] = Kr[lane + 64*j];
    fft320<1>(v, lane);
    const float2* mr = maps + (((size_t)b*NC + c)*NH + h)*NW;
    #pragma unroll
    for (int k1=0;k1<5;k1++){
      int n = k1 + 5*br;
      float2 m = mr[n];
      float2 t = make_float2(m.x*v[k1].x + m.y*v[k1].y, m.x*v[k1].y - m.y*v[k1].x);
      float sg = ((h + n) & 1) ? -1.f : 1.f;
      acc[k1].x += t.x*sg; acc[k1].y += t.y*sg;
    }
  }
  #pragma unroll
  for (int k1=0;k1<5;k1++) acc_lds[wid][k1 + 5*br] = acc[k1];
  __syncthreads();
  float partial = 0.f;
  const float2* prow = AOP ? (p + ((size_t)b*NH + h)*NW) : (const float2*)nullptr;
  float2* orow = out + ((size_t)b*NH + h)*NW;
  for (int n = tid; n < NW; n += 256){
    float2 s;
    s.x = acc_lds[0][n].x + acc_lds[1][n].x + acc_lds[2][n].x + acc_lds[3][n].x;
    s.y = acc_lds[0][n].y + acc_lds[1][n].y + acc_lds[2][n].y + acc_lds[3][n].y;
    if (AOP){
      float2 pv = prow[n];
      s.x += L2LAMF * pv.x; s.y += L2LAMF * pv.y;
      partial += pv.x*s.x + pv.y*s.y;
    }
    orow[n] = s;
  }
  if (AOP){
    #pragma unroll
    for (int o=32;o>0;o>>=1) partial += __shfl_down(partial, o, 64);
    if (lane == 0) red[wid] = partial;
    __syncthreads();
    if (tid == 0) atomicAdd(&pAp[b], red[0]+red[1]+red[2]+red[3]);
  }
}

// ---------- weight prepack: w2 [oc][ic][3][3] fp32 -> wpk [tap][oc][ic] bf16 ----------
__global__ __launch_bounds__(256) void k_prepw2(const float* __restrict__ w2,
                                                __hip_bfloat16* __restrict__ wpk){
  int i = blockIdx.x*256 + threadIdx.x;
  if (i < 9*64*64){
    int t = i / 4096; int rem = i & 4095; int oc = rem >> 6; int ic = rem & 63;
    wpk[i] = __float2bfloat16(w2[oc*576 + ic*9 + t]);
  }
}

// ---------- conv1: 2->64, channel-last h1; acc[16] x 4 oc-group passes (no spill) ----------
__global__ __launch_bounds__(256) void k_conv1(const float2* __restrict__ xin,
                                               const float* __restrict__ w1,
                                               const float* __restrict__ b1,
                                               __hip_bfloat16* __restrict__ h1, int b0){
  __shared__ float2 tin[18][19];
  __shared__ float wts[64*18];
  __shared__ float bia[64];
  int bg = blockIdx.z; int b = b0 + bg;
  int bx = blockIdx.x*16, by = blockIdx.y*16;
  int tid = threadIdx.x;
  for (int i = tid; i < 64*18; i += 256) wts[i] = w1[i];
  if (tid < 64) bia[tid] = b1[tid];
  for (int i = tid; i < 18*18; i += 256){
    int iy = i/18, ix = i%18; int gy = by+iy-1, gx = bx+ix-1;
    float2 t = make_float2(0.f, 0.f);
    if (gy>=0 && gy<NH && gx>=0 && gx<NW) t = xin[((size_t)b*NH + gy)*NW + gx];
    tin[iy][ix] = t;
  }
  __syncthreads();
  int px = tid & 15, py = tid >> 4;
  float2 iv[3][3];
  #pragma unroll
  for (int dy=0;dy<3;dy++)
  #pragma unroll
  for (int dx=0;dx<3;dx++) iv[dy][dx] = tin[py+dy][px+dx];
  int gy = by+py, gx = bx+px;
  size_t base = (((size_t)bg*NH + gy)*NW + gx)*64;
  #pragma unroll
  for (int g4=0; g4<4; g4++){
    float acc[16];
    #pragma unroll
    for (int o=0;o<16;o++) acc[o] = bia[g4*16+o];
    #pragma unroll
    for (int dy=0;dy<3;dy++)
    #pragma unroll
    for (int dx=0;dx<3;dx++){
      float2 v = iv[dy][dx];
      int tap = dy*3+dx;
      #pragma unroll
      for (int o=0;o<16;o++)
        acc[o] += v.x * wts[(g4*16+o)*18 + tap] + v.y * wts[(g4*16+o)*18 + 9 + tap];
    }
    #pragma unroll
    for (int o4=0;o4<4;o4++){
      ushort4 pk;
      pk.x = f2bf(fmaxf(acc[o4*4+0], 0.f));
      pk.y = f2bf(fmaxf(acc[o4*4+1], 0.f));
      pk.z = f2bf(fmaxf(acc[o4*4+2], 0.f));
      pk.w = f2bf(fmaxf(acc[o4*4+3], 0.f));
      *(ushort4*)(h1 + base + g4*16 + o4*4) = pk;
    }
  }
}

// ---------- conv2 (MFMA implicit GEMM): 64->64, h1/h2 channel-last bf16 ----------
// Block: 8x8 px x 64 oc. 4 waves: wave w -> oc [16w,16w+16). K = 9 taps x 64 ic.
__global__ __launch_bounds__(256) void k_conv2(const __hip_bfloat16* __restrict__ h1,
                                               const __hip_bfloat16* __restrict__ wpk,
                                               const float* __restrict__ b2,
                                               __hip_bfloat16* __restrict__ h2){
  __shared__ __align__(16) short tile[100][64];   // [sp][ic], ic-blk ^ (sp&7)
  __shared__ __align__(16) short wlds[3][64][64]; // [t][oc][ic], ic-blk ^ (oc&7)
  int tid = threadIdx.x; int lane = tid & 63; int wid = tid >> 6;
  int bg = blockIdx.z;
  int x0 = blockIdx.x*8, y0 = blockIdx.y*8;
  // stage input tile (10x10 halo), zero-pad OOB
  for (int i = tid; i < 800; i += 256){
    int sp = i >> 3, blk = i & 7;
    int yy = sp / 10, xx = sp % 10;
    int gy = y0 + yy - 1, gx = x0 + xx - 1;
    uint4 val = make_uint4(0u,0u,0u,0u);
    if (gy>=0 && gy<NH && gx>=0 && gx<NW)
      val = *(const uint4*)(h1 + (((size_t)bg*NH + gy)*NW + gx)*64 + blk*8);
    *(uint4*)&tile[sp][(blk ^ (sp & 7))*8] = val;
  }
  f32x4 acc[4];
  #pragma unroll
  for (int n=0;n<4;n++) acc[n] = (f32x4){0.f,0.f,0.f,0.f};
  #pragma unroll
  for (int c = 0; c < 3; c++){
    __syncthreads();
    for (int i = tid; i < 1536; i += 256){
      int t = i >> 9; int rem = i & 511; int oc = rem >> 3; int blk = rem & 7;
      uint4 val = *(const uint4*)(wpk + (size_t)(3*c + t)*4096 + oc*64 + blk*8);
      *(uint4*)&wlds[t][oc][(blk ^ (oc & 7))*8] = val;
    }
    __syncthreads();
    #pragma unroll
    for (int t=0;t<3;t++){
      int tap = 3*c + t;
      int dy = tap / 3, dx = tap % 3;
      #pragma unroll
      for (int kh=0; kh<2; kh++){
        int icblk = kh*4 + (lane >> 4);
        int oc = wid*16 + (lane & 15);
        bf16x8 afr = *(bf16x8*)&wlds[t][oc][(icblk ^ (oc & 7))*8];
        #pragma unroll
        for (int n=0;n<4;n++){
          int px = n*16 + (lane & 15);
          int sp = ((px >> 3) + dy)*10 + (px & 7) + dx;
          bf16x8 bfr = *(bf16x8*)&tile[sp][(icblk ^ (sp & 7))*8];
          acc[n] = __builtin_amdgcn_mfma_f32_16x16x32_bf16(afr, bfr, acc[n], 0, 0, 0);
        }
      }
    }
  }
  // epilogue: D col=lane&15 -> px, row=(lane>>4)*4+reg -> oc
  int oc0 = wid*16 + (lane >> 4)*4;
  float b4[4];
  #pragma unroll
  for (int r=0;r<4;r++) b4[r] = b2[oc0 + r];
  #pragma unroll
  for (int n=0;n<4;n++){
    int px = n*16 + (lane & 15);
    int gy = y0 + (px >> 3), gx = x0 + (px & 7);
    ushort4 pk;
    pk.x = f2bf(fmaxf(acc[n][0] + b4[0], 0.f));
    pk.y = f2bf(fmaxf(acc[n][1] + b4[1], 0.f));
    pk.z = f2bf(fmaxf(acc[n][2] + b4[2], 0.f));
    pk.w = f2bf(fmaxf(acc[n][3] + b4[3], 0.f));
    *(ushort4*)(h2 + (((size_t)bg*NH + gy)*NW + gx)*64 + oc0) = pk;
  }
}

// ---------- conv3: 64->2, reads h2 channel-last; rhs in-place over xadj ----------
__global__ __launch_bounds__(256) void k_conv3(const __hip_bfloat16* __restrict__ h2,
                                               const float* __restrict__ w3,
                                               const float* __restrict__ b3,
                                               float2* __restrict__ xr,
                                               const float2* __restrict__ xin, int b0){
  __shared__ __align__(16) short tile[324][64];  // [sp][ic], ic-blk ^ (sp&7)
  __shared__ float w3s[2][576];
  int tid = threadIdx.x;
  int bg = blockIdx.z; int b = b0 + bg;
  int x0 = blockIdx.x*16, y0 = blockIdx.y*16;
  for (int i = tid; i < 1152; i += 256) w3s[i/576][i%576] = w3[i];
  for (int i = tid; i < 2592; i += 256){
    int sp = i >> 3, blk = i & 7;
    int yy = sp / 18, xx = sp % 18;
    int gy = y0 + yy - 1, gx = x0 + xx - 1;
    uint4 val = make_uint4(0u,0u,0u,0u);
    if (gy>=0 && gy<NH && gx>=0 && gx<NW)
      val = *(const uint4*)(h2 + (((size_t)bg*NH + gy)*NW + gx)*64 + blk*8);
    *(uint4*)&tile[sp][(blk ^ (sp & 7))*8] = val;
  }
  __syncthreads();
  int px = tid & 15, py = tid >> 4;
  float a0 = 0.f, a1 = 0.f;
  #pragma unroll
  for (int dy=0;dy<3;dy++)
  #pragma unroll
  for (int dx=0;dx<3;dx++){
    int sp = (py+dy)*18 + px + dx;
    int tap = dy*3 + dx;
    #pragma unroll
    for (int blk=0;blk<8;blk++){
      bf16x8 v8 = *(bf16x8*)&tile[sp][(blk ^ (sp & 7))*8];
      #pragma unroll
      for (int j=0;j<8;j++){
        float v = bfbits2f(v8[j]);
        int ic = blk*8 + j;
        a0 += v * w3s[0][ic*9 + tap];
        a1 += v * w3s[1][ic*9 + tap];
      }
    }
  }
  int gy = y0 + py, gx = x0 + px;
  size_t g = ((size_t)b*NH + gy)*NW + gx;
  float2 xa = xr[g]; float2 xv = xin[g];
  float2 o;
  o.x = xa.x + L2LAMF * (xv.x + a0 + b3[0]);
  o.y = xa.y + L2LAMF * (xv.y + a1 + b3[1]);
  xr[g] = o;
}

// ---------- CG glue ----------
__global__ __launch_bounds__(256) void k_cginit(const float2* __restrict__ rhs,
                                                const float2* __restrict__ Ax0,
                                                const float2* __restrict__ x0,
                                                float2* __restrict__ x,
                                                float2* __restrict__ r,
                                                float2* __restrict__ p,
                                                float* __restrict__ rs){
  __shared__ float red[4];
  int tid = threadIdx.x;
  int b = blockIdx.x / 400; int e = (blockIdx.x % 400)*256 + tid;
  size_t g = (size_t)b*NH*NW + e;
  float2 rh = rhs[g], ax = Ax0[g];
  float2 rv = make_float2(rh.x - ax.x, rh.y - ax.y);
  r[g] = rv; p[g] = rv; x[g] = x0[g];
  float partial = rv.x*rv.x + rv.y*rv.y;
  int lane = tid & 63, wid = tid >> 6;
  #pragma unroll
  for (int o=32;o>0;o>>=1) partial += __shfl_down(partial, o, 64);
  if (lane == 0) red[wid] = partial;
  __syncthreads();
  if (tid == 0) atomicAdd(&rs[b], red[0]+red[1]+red[2]+red[3]);
}

__global__ __launch_bounds__(256) void k_cgupdate(float2* __restrict__ x,
                                                  float2* __restrict__ r,
                                                  const float2* __restrict__ p,
                                                  const float2* __restrict__ Ap,
                                                  const float* __restrict__ rs_old,
                                                  const float* __restrict__ pAp,
                                                  float* __restrict__ rs_new){
  __shared__ float red[4];
  int tid = threadIdx.x;
  int b = blockIdx.x / 400; int e = (blockIdx.x % 400)*256 + tid;
  size_t g = (size_t)b*NH*NW + e;
  float alpha = rs_old[b] / pAp[b];
  float2 xv = x[g], pv = p[g], rv = r[g], av = Ap[g];
  xv.x += alpha*pv.x; xv.y += alpha*pv.y;
  rv.x -= alpha*av.x; rv.y -= alpha*av.y;
  x[g] = xv; r[g] = rv;
  float partial = rv.x*rv.x + rv.y*rv.y;
  int lane = tid & 63, wid = tid >> 6;
  #pragma unroll
  for (int o=32;o>0;o>>=1) partial += __shfl_down(partial, o, 64);
  if (lane == 0) red[wid] = partial;
  __syncthreads();
  if (tid == 0) atomicAdd(&rs_new[b], red[0]+red[1]+red[2]+red[3]);
}

__global__ __launch_bounds__(256) void k_cgp(float2* __restrict__ p,
                                             const float2* __restrict__ r,
                                             const float* __restrict__ rs_new,
                                             const float* __restrict__ rs_old){
  int tid = threadIdx.x;
  int b = blockIdx.x / 400; int e = (blockIdx.x % 400)*256 + tid;
  size_t g = (size_t)b*NH*NW + e;
  float beta = rs_new[b] / rs_old[b];
  float2 rv = r[g], pv = p[g];
  p[g] = make_float2(rv.x + beta*pv.x, rv.y + beta*pv.y);
}

extern "C" void kernel_launch(void* const* d_in, const int* in_sizes, int n_in,
                              void* d_out, int out_size, void* d_ws, size_t ws_size,
                              hipStream_t stream) {
  (void)in_sizes; (void)n_in; (void)out_size;
  const float2* x_in = (const float2*)d_in[0];
  const float2* maps = (const float2*)d_in[1];
  const float*  masks= (const float*)d_in[2];
  const float2* ksp  = (const float2*)d_in[3];
  const float* w1 = (const float*)d_in[4]; const float* b1 = (const float*)d_in[5];
  const float* w2 = (const float*)d_in[6]; const float* b2 = (const float*)d_in[7];
  const float* w3 = (const float*)d_in[8]; const float* b3 = (const float*)d_in[9];
  float2* xout = (float2*)d_out;

  const size_t VECB = (size_t)NB*NH*NW*sizeof(float2);          // 6.55 MB
  const size_t PERB = (size_t)NC*NH*NW*sizeof(float2);          // 9.83 MB (K per batch)
  const size_t HBUF = (size_t)64*NH*NW*sizeof(__hip_bfloat16);  // 13.1 MB (h per batch)
  const size_t WPKB = (size_t)9*64*64*sizeof(__hip_bfloat16);   // 73.7 KB
  auto rnd = [](size_t x){ return (x + 255) & ~(size_t)255; };
  size_t fixed = 4*rnd(VECB) + rnd(4096) + rnd(WPKB);
  int G = 8;
  while (G > 1 && fixed + rnd((size_t)G*PERB) > ws_size) G >>= 1;
  int DEN_G = 8;
  while (DEN_G > 1 &&
         fixed + rnd((size_t)G*PERB > (size_t)DEN_G*2*HBUF ? (size_t)G*PERB
                                                           : (size_t)DEN_G*2*HBUF) > ws_size)
    DEN_G >>= 1;
  size_t region = (size_t)G*PERB;
  if ((size_t)DEN_G*2*HBUF > region) region = (size_t)DEN_G*2*HBUF;

  char* ws = (char*)d_ws;
  size_t off = 0;
  auto alloc = [&](size_t bytes)->void*{ void* p = ws + off; off += rnd(bytes); return p; };
  float2* xr   = (float2*)alloc(VECB);   // xadj -> rhs (in-place)
  float2* Ap   = (float2*)alloc(VECB);
  float2* rbuf = (float2*)alloc(VECB);
  float2* pbuf = (float2*)alloc(VECB);
  float*  scal = (float*)alloc(4096);    // rs[i*8+b]; pAp at +64
  __hip_bfloat16* wpk = (__hip_bfloat16*)alloc(WPKB);
  void*   shrd = alloc(region);          // K during FFT phases; h1/h2 during denoise
  float2* K = (float2*)shrd;
  __hip_bfloat16* h1 = (__hip_bfloat16*)shrd;
  __hip_bfloat16* h2 = h1 + (size_t)DEN_G*64*NH*NW;
  hipMemsetAsync(scal, 0, 4096, stream);

  const int gCol = G*NC*40;
  const int gRow = G*NC*NH/8;
  const int gIC  = G*NH;

  // adjoint: xadj -> xr  (uses K)
  for (int b0 = 0; b0 < NB; b0 += G){
    k_adjCol<<<gCol, 512, 0, stream>>>(ksp, masks, K, b0);
    k_rowIC<false><<<gIC, 256, 0, stream>>>(K, maps, nullptr, xr, nullptr, b0);
  }
  // denoiser: xr = xadj + lam*(x + CNN(x))  (K dead; region holds h1/h2)
  k_prepw2<<<144, 256, 0, stream>>>(w2, wpk);
  for (int b0 = 0; b0 < NB; b0 += DEN_G){
    k_conv1<<<dim3(20,20,DEN_G), 256, 0, stream>>>(x_in, w1, b1, h1, b0);
    k_conv2<<<dim3(40,40,DEN_G), 256, 0, stream>>>(h1, wpk, b2, h2);
    k_conv3<<<dim3(20,20,DEN_G), 256, 0, stream>>>(h2, w3, b3, xr, x_in, b0);
  }
  // Aop(x0) -> Ap
  for (int b0 = 0; b0 < NB; b0 += G){
    k_rowF<<<gRow, 512, 0, stream>>>(x_in, maps, K, b0);
    k_colFMI<<<gCol, 512, 0, stream>>>(K, masks, b0);
    k_rowIC<true><<<gIC, 256, 0, stream>>>(K, maps, x_in, Ap, scal + 64, b0);
  }
  // r = rhs - Ax0; p = r; x = x0; rs0
  k_cginit<<<3200, 256, 0, stream>>>(xr, Ap, x_in, xout, rbuf, pbuf, scal);
  // 6 CG iterations
  for (int i = 1; i <= 6; i++){
    for (int b0 = 0; b0 < NB; b0 += G){
      k_rowF<<<gRow, 512, 0, stream>>>(pbuf, maps, K, b0);
      k_colFMI<<<gCol, 512, 0, stream>>>(K, masks, b0);
      k_rowIC<true><<<gIC, 256, 0, stream>>>(K, maps, pbuf, Ap, scal + 64 + i*8, b0);
    }
    k_cgupdate<<<3200, 256, 0, stream>>>(xout, rbuf, pbuf, Ap,
                                         scal + (i-1)*8, scal + 64 + i*8, scal + i*8);
    if (i < 6)
      k_cgp<<<3200, 256, 0, stream>>>(pbuf, rbuf, scal + i*8, scal + (i-1)*8);
  }
}

// Round 12
// 2016.273 us; speedup vs baseline: 13.0789x; 1.1310x over previous
//
#include <hip/hip_runtime.h>
#include <hip/hip_bf16.h>

#define NB 8
#define NC 12
#define NH 320
#define NW 320
#define L2LAMF 0.05f
#define SCALE_NORMAL (1.0f/(320.0f*320.0f))
#define SCALE_ADJ (1.0f/320.0f)

typedef __attribute__((ext_vector_type(8))) short bf16x8;
typedef __attribute__((ext_vector_type(4))) float f32x4;

__device__ __forceinline__ float2 cmulf(float2 a, float2 b){
  return make_float2(a.x*b.x - a.y*b.y, a.x*b.y + a.y*b.x);
}
__device__ __forceinline__ unsigned short f2bf(float f){
  __hip_bfloat16 h = __float2bfloat16(f);
  return *reinterpret_cast<unsigned short*>(&h);
}
__device__ __forceinline__ float bfbits2f(short s){
  unsigned u = ((unsigned)(unsigned short)s) << 16;
  return __uint_as_float(u);
}

// 320-point FFT: radix-5 in regs + 64-point DIF across the wave's lanes.
// Input: v[j] = x[lane + 64*j]. Output: v[k1] holds X[k1 + 5*brev6(lane)].
template<int S>
__device__ __forceinline__ void fft320(float2 v[5], int lane){
  const float PI = 3.14159265358979323846f;
  const float C1 = 0.30901699437494742f, S1 = 0.95105651629515357f;
  const float C2 = -0.80901699437494745f, S2 = 0.58778525229247314f;
  const float2 w5[5] = { make_float2(1.f,0.f), make_float2(C1, S*S1),
                         make_float2(C2, S*S2), make_float2(C2, -S*S2),
                         make_float2(C1, -S*S1) };
  float2 y[5];
  #pragma unroll
  for (int k=0;k<5;k++){
    float2 s = v[0];
    #pragma unroll
    for (int n=1;n<5;n++){
      float2 t = cmulf(v[n], w5[(n*k)%5]);
      s.x += t.x; s.y += t.y;
    }
    y[k] = s;
  }
  float ang = (float)S * (2.f*PI) * (float)lane * (1.f/320.f);
  float sn, cs; __sincosf(ang, &sn, &cs);
  float2 wt = make_float2(cs, sn);
  float2 t2 = wt;
  y[1] = cmulf(y[1], t2);
  t2 = cmulf(t2, wt); y[2] = cmulf(y[2], t2);
  t2 = cmulf(t2, wt); y[3] = cmulf(y[3], t2);
  t2 = cmulf(t2, wt); y[4] = cmulf(y[4], t2);
  #pragma unroll
  for (int h=32; h>=1; h>>=1){
    int j = lane & (h-1);
    bool up = (lane & h) != 0;
    float a2 = (float)S * PI * (float)j / (float)h;
    float ws, wc; __sincosf(a2, &ws, &wc);
    float2 w = make_float2(wc, ws);
    #pragma unroll
    for (int q=0;q<5;q++){
      float2 a = y[q];
      float2 b;
      b.x = __shfl_xor(a.x, h, 64);
      b.y = __shfl_xor(a.y, h, 64);
      float2 sum = make_float2(a.x+b.x, a.y+b.y);
      float2 dif = make_float2(b.x-a.x, b.y-a.y);
      float2 rot = cmulf(dif, w);
      y[q] = up ? rot : sum;
    }
  }
  #pragma unroll
  for (int q=0;q<5;q++) v[q] = y[q];
}

// ---------- coil-mult + (-1)^{h+w} + forward row FFT ----------
__global__ __launch_bounds__(512) void k_rowF(const float2* __restrict__ xin,
                                              const float2* __restrict__ maps,
                                              float2* __restrict__ K, int b0){
  __shared__ float2 lds[8][321];
  int tid = threadIdx.x; int wid = tid >> 6; int lane = tid & 63;
  int row = blockIdx.x * 8 + wid;
  int h = row % NH; int bc = row / NH; int c = bc % NC; int bg = bc / NC;
  int b = b0 + bg;
  const float2* xr = xin + ((size_t)b*NH + h)*NW;
  const float2* mr = maps + (((size_t)b*NC + c)*NH + h)*NW;
  float2 v[5];
  #pragma unroll
  for (int j=0;j<5;j++){
    int n = lane + 64*j;
    float2 t = cmulf(mr[n], xr[n]);
    float sg = ((h + n) & 1) ? -1.f : 1.f;
    v[j] = make_float2(t.x*sg, t.y*sg);
  }
  fft320<-1>(v, lane);
  int br = __brev((unsigned)lane) >> 26;
  #pragma unroll
  for (int k1=0;k1<5;k1++) lds[wid][k1 + 5*br] = v[k1];
  float2* Kr = K + (((size_t)(bg*NC + c))*NH + h)*NW;
  #pragma unroll
  for (int j=0;j<5;j++){ int n = lane + 64*j; Kr[n] = lds[wid][n]; }
}

// ---------- column FFT -> mask*scale -> column IFFT (in place) ----------
__global__ __launch_bounds__(512) void k_colFMI(float2* __restrict__ K,
                                                const float* __restrict__ masks, int b0){
  __shared__ float2 tile[8][321];
  int tid = threadIdx.x;
  int bid = blockIdx.x;
  int ct = bid % 40; int c = (bid/40) % NC; int bg = bid/(40*NC);
  int b = b0 + bg;
  int col0 = ct * 8;
  float2* base = K + ((size_t)(bg*NC + c))*NH*NW;
  #pragma unroll
  for (int it=0; it<5; it++){
    int e = tid + 512*it; int hh = e >> 3; int ci = e & 7;
    tile[ci][hh] = base[(size_t)hh*NW + col0 + ci];
  }
  __syncthreads();
  int wid = tid >> 6, lane = tid & 63;
  int col = col0 + wid;
  float2 v[5];
  #pragma unroll
  for (int j=0;j<5;j++) v[j] = tile[wid][lane + 64*j];
  fft320<-1>(v, lane);
  int br = __brev((unsigned)lane) >> 26;
  const float* mb = masks + (size_t)b*NH*NW + col;
  #pragma unroll
  for (int k1=0;k1<5;k1++){
    int kh = k1 + 5*br;
    float mv = mb[(size_t)kh*NW] * SCALE_NORMAL;
    v[k1].x *= mv; v[k1].y *= mv;
    tile[wid][kh] = v[k1];
  }
  #pragma unroll
  for (int j=0;j<5;j++) v[j] = tile[wid][lane + 64*j];
  fft320<1>(v, lane);
  #pragma unroll
  for (int k1=0;k1<5;k1++) tile[wid][k1 + 5*br] = v[k1];
  __syncthreads();
  #pragma unroll
  for (int it=0; it<5; it++){
    int e = tid + 512*it; int hh = e >> 3; int ci = e & 7;
    base[(size_t)hh*NW + col0 + ci] = tile[ci][hh];
  }
}

// ---------- adjoint column: (-1)^{kh+kw}*mask*(1/320) then column IFFT ----------
__global__ __launch_bounds__(512) void k_adjCol(const float2* __restrict__ ksp,
                                                const float* __restrict__ masks,
                                                float2* __restrict__ K, int b0){
  __shared__ float2 tile[8][321];
  int tid = threadIdx.x;
  int bid = blockIdx.x;
  int ct = bid % 40; int c = (bid/40) % NC; int bg = bid/(40*NC);
  int b = b0 + bg;
  int col0 = ct * 8;
  const float2* src = ksp + ((size_t)(b*NC + c))*NH*NW;
  float2* dst = K + ((size_t)(bg*NC + c))*NH*NW;
  #pragma unroll
  for (int it=0; it<5; it++){
    int e = tid + 512*it; int hh = e >> 3; int ci = e & 7;
    tile[ci][hh] = src[(size_t)hh*NW + col0 + ci];
  }
  __syncthreads();
  int wid = tid >> 6, lane = tid & 63;
  int col = col0 + wid;
  const float* mb = masks + (size_t)b*NH*NW + col;
  float2 v[5];
  #pragma unroll
  for (int j=0;j<5;j++){
    int hh = lane + 64*j;
    float2 t = tile[wid][hh];
    float mv = mb[(size_t)hh*NW] * (((hh + col) & 1) ? -SCALE_ADJ : SCALE_ADJ);
    v[j] = make_float2(t.x*mv, t.y*mv);
  }
  fft320<1>(v, lane);
  int br = __brev((unsigned)lane) >> 26;
  #pragma unroll
  for (int k1=0;k1<5;k1++) tile[wid][k1 + 5*br] = v[k1];
  __syncthreads();
  #pragma unroll
  for (int it=0; it<5; it++){
    int e = tid + 512*it; int hh = e >> 3; int ci = e & 7;
    dst[(size_t)hh*NW + col0 + ci] = tile[ci][hh];
  }
}

// ---------- row IFFT + (-1)^{h+w} + conj(maps) combine (+ lam*p, pAp) ----------
template<bool AOP>
__global__ __launch_bounds__(256) void k_rowIC(const float2* __restrict__ K,
                                               const float2* __restrict__ maps,
                                               const float2* __restrict__ p,
                                               float2* __restrict__ out,
                                               float* __restrict__ pAp, int b0){
  __shared__ float2 acc_lds[4][321];
  __shared__ float red[4];
  int tid = threadIdx.x; int wid = tid >> 6; int lane = tid & 63;
  int bg = blockIdx.x / NH; int h = blockIdx.x % NH;
  int b = b0 + bg;
  int br = __brev((unsigned)lane) >> 26;
  float2 acc[5];
  #pragma unroll
  for (int k1=0;k1<5;k1++) acc[k1] = make_float2(0.f, 0.f);
  for (int c = wid; c < NC; c += 4){
    const float2* Kr = K + (((size_t)(bg*NC + c))*NH + h)*NW;
    float2 v[5];
    #pragma unroll
    for (int j=0;j<5;j++) v[j] = Kr[lane + 64*j];
    fft320<1>(v, lane);
    const float2* mr = maps + (((size_t)b*NC + c)*NH + h)*NW;
    #pragma unroll
    for (int k1=0;k1<5;k1++){
      int n = k1 + 5*br;
      float2 m = mr[n];
      float2 t = make_float2(m.x*v[k1].x + m.y*v[k1].y, m.x*v[k1].y - m.y*v[k1].x);
      float sg = ((h + n) & 1) ? -1.f : 1.f;
      acc[k1].x += t.x*sg; acc[k1].y += t.y*sg;
    }
  }
  #pragma unroll
  for (int k1=0;k1<5;k1++) acc_lds[wid][k1 + 5*br] = acc[k1];
  __syncthreads();
  float partial = 0.f;
  const float2* prow = AOP ? (p + ((size_t)b*NH + h)*NW) : (const float2*)nullptr;
  float2* orow = out + ((size_t)b*NH + h)*NW;
  for (int n = tid; n < NW; n += 256){
    float2 s;
    s.x = acc_lds[0][n].x + acc_lds[1][n].x + acc_lds[2][n].x + acc_lds[3][n].x;
    s.y = acc_lds[0][n].y + acc_lds[1][n].y + acc_lds[2][n].y + acc_lds[3][n].y;
    if (AOP){
      float2 pv = prow[n];
      s.x += L2LAMF * pv.x; s.y += L2LAMF * pv.y;
      partial += pv.x*s.x + pv.y*s.y;
    }
    orow[n] = s;
  }
  if (AOP){
    #pragma unroll
    for (int o=32;o>0;o>>=1) partial += __shfl_down(partial, o, 64);
    if (lane == 0) red[wid] = partial;
    __syncthreads();
    if (tid == 0) atomicAdd(&pAp[b], red[0]+red[1]+red[2]+red[3]);
  }
}

// ---------- weight prepack: w2 [oc][ic][3][3] fp32 -> wpk [tap][oc][ic] bf16 ----------
__global__ __launch_bounds__(256) void k_prepw2(const float* __restrict__ w2,
                                                __hip_bfloat16* __restrict__ wpk){
  int i = blockIdx.x*256 + threadIdx.x;
  if (i < 9*64*64){
    int t = i / 4096; int rem = i & 4095; int oc = rem >> 6; int ic = rem & 63;
    wpk[i] = __float2bfloat16(w2[oc*576 + ic*9 + t]);
  }
}

// ---------- conv1: 2->64, channel-last h1; acc[16] x 4 oc-group passes (no spill) ----------
__global__ __launch_bounds__(256) void k_conv1(const float2* __restrict__ xin,
                                               const float* __restrict__ w1,
                                               const float* __restrict__ b1,
                                               __hip_bfloat16* __restrict__ h1, int b0){
  __shared__ float2 tin[18][19];
  __shared__ float wts[64*18];
  __shared__ float bia[64];
  int bg = blockIdx.z; int b = b0 + bg;
  int bx = blockIdx.x*16, by = blockIdx.y*16;
  int tid = threadIdx.x;
  for (int i = tid; i < 64*18; i += 256) wts[i] = w1[i];
  if (tid < 64) bia[tid] = b1[tid];
  for (int i = tid; i < 18*18; i += 256){
    int iy = i/18, ix = i%18; int gy = by+iy-1, gx = bx+ix-1;
    float2 t = make_float2(0.f, 0.f);
    if (gy>=0 && gy<NH && gx>=0 && gx<NW) t = xin[((size_t)b*NH + gy)*NW + gx];
    tin[iy][ix] = t;
  }
  __syncthreads();
  int px = tid & 15, py = tid >> 4;
  float2 iv[3][3];
  #pragma unroll
  for (int dy=0;dy<3;dy++)
  #pragma unroll
  for (int dx=0;dx<3;dx++) iv[dy][dx] = tin[py+dy][px+dx];
  int gy = by+py, gx = bx+px;
  size_t base = (((size_t)bg*NH + gy)*NW + gx)*64;
  #pragma unroll
  for (int g4=0; g4<4; g4++){
    float acc[16];
    #pragma unroll
    for (int o=0;o<16;o++) acc[o] = bia[g4*16+o];
    #pragma unroll
    for (int dy=0;dy<3;dy++)
    #pragma unroll
    for (int dx=0;dx<3;dx++){
      float2 v = iv[dy][dx];
      int tap = dy*3+dx;
      #pragma unroll
      for (int o=0;o<16;o++)
        acc[o] += v.x * wts[(g4*16+o)*18 + tap] + v.y * wts[(g4*16+o)*18 + 9 + tap];
    }
    #pragma unroll
    for (int o4=0;o4<4;o4++){
      ushort4 pk;
      pk.x = f2bf(fmaxf(acc[o4*4+0], 0.f));
      pk.y = f2bf(fmaxf(acc[o4*4+1], 0.f));
      pk.z = f2bf(fmaxf(acc[o4*4+2], 0.f));
      pk.w = f2bf(fmaxf(acc[o4*4+3], 0.f));
      *(ushort4*)(h1 + base + g4*16 + o4*4) = pk;
    }
  }
}

// ---------- conv2 (MFMA implicit GEMM): 64->64, h1/h2 channel-last bf16 ----------
// Block: 8x8 px x 64 oc. 4 waves: wave w -> oc [16w,16w+16). K = 9 taps x 64 ic.
__global__ __launch_bounds__(256) void k_conv2(const __hip_bfloat16* __restrict__ h1,
                                               const __hip_bfloat16* __restrict__ wpk,
                                               const float* __restrict__ b2,
                                               __hip_bfloat16* __restrict__ h2){
  __shared__ __align__(16) short tile[100][64];   // [sp][ic], ic-blk ^ (sp&7)
  __shared__ __align__(16) short wlds[3][64][64]; // [t][oc][ic], ic-blk ^ (oc&7)
  int tid = threadIdx.x; int lane = tid & 63; int wid = tid >> 6;
  int bg = blockIdx.z;
  int x0 = blockIdx.x*8, y0 = blockIdx.y*8;
  // stage input tile (10x10 halo), zero-pad OOB
  for (int i = tid; i < 800; i += 256){
    int sp = i >> 3, blk = i & 7;
    int yy = sp / 10, xx = sp % 10;
    int gy = y0 + yy - 1, gx = x0 + xx - 1;
    uint4 val = make_uint4(0u,0u,0u,0u);
    if (gy>=0 && gy<NH && gx>=0 && gx<NW)
      val = *(const uint4*)(h1 + (((size_t)bg*NH + gy)*NW + gx)*64 + blk*8);
    *(uint4*)&tile[sp][(blk ^ (sp & 7))*8] = val;
  }
  f32x4 acc[4];
  #pragma unroll
  for (int n=0;n<4;n++) acc[n] = (f32x4){0.f,0.f,0.f,0.f};
  #pragma unroll
  for (int c = 0; c < 3; c++){
    __syncthreads();
    for (int i = tid; i < 1536; i += 256){
      int t = i >> 9; int rem = i & 511; int oc = rem >> 3; int blk = rem & 7;
      uint4 val = *(const uint4*)(wpk + (size_t)(3*c + t)*4096 + oc*64 + blk*8);
      *(uint4*)&wlds[t][oc][(blk ^ (oc & 7))*8] = val;
    }
    __syncthreads();
    #pragma unroll
    for (int t=0;t<3;t++){
      int tap = 3*c + t;
      int dy = tap / 3, dx = tap % 3;
      #pragma unroll
      for (int kh=0; kh<2; kh++){
        int icblk = kh*4 + (lane >> 4);
        int oc = wid*16 + (lane & 15);
        bf16x8 afr = *(bf16x8*)&wlds[t][oc][(icblk ^ (oc & 7))*8];
        #pragma unroll
        for (int n=0;n<4;n++){
          int px = n*16 + (lane & 15);
          int sp = ((px >> 3) + dy)*10 + (px & 7) + dx;
          bf16x8 bfr = *(bf16x8*)&tile[sp][(icblk ^ (sp & 7))*8];
          acc[n] = __builtin_amdgcn_mfma_f32_16x16x32_bf16(afr, bfr, acc[n], 0, 0, 0);
        }
      }
    }
  }
  // epilogue: D col=lane&15 -> px, row=(lane>>4)*4+reg -> oc
  int oc0 = wid*16 + (lane >> 4)*4;
  float b4[4];
  #pragma unroll
  for (int r=0;r<4;r++) b4[r] = b2[oc0 + r];
  #pragma unroll
  for (int n=0;n<4;n++){
    int px = n*16 + (lane & 15);
    int gy = y0 + (px >> 3), gx = x0 + (px & 7);
    ushort4 pk;
    pk.x = f2bf(fmaxf(acc[n][0] + b4[0], 0.f));
    pk.y = f2bf(fmaxf(acc[n][1] + b4[1], 0.f));
    pk.z = f2bf(fmaxf(acc[n][2] + b4[2], 0.f));
    pk.w = f2bf(fmaxf(acc[n][3] + b4[3], 0.f));
    *(ushort4*)(h2 + (((size_t)bg*NH + gy)*NW + gx)*64 + oc0) = pk;
  }
}

// ---------- conv3: 64->2; blk-outer loop (unroll 1) to cap live regs ----------
__global__ __launch_bounds__(256) void k_conv3(const __hip_bfloat16* __restrict__ h2,
                                               const float* __restrict__ w3,
                                               const float* __restrict__ b3,
                                               float2* __restrict__ xr,
                                               const float2* __restrict__ xin, int b0){
  __shared__ __align__(16) short tile[324][64];  // [sp][ic], ic-blk ^ (sp&7)
  __shared__ float w3s[2][576];
  int tid = threadIdx.x;
  int bg = blockIdx.z; int b = b0 + bg;
  int x0 = blockIdx.x*16, y0 = blockIdx.y*16;
  for (int i = tid; i < 1152; i += 256) w3s[i/576][i%576] = w3[i];
  for (int i = tid; i < 2592; i += 256){
    int sp = i >> 3, blk = i & 7;
    int yy = sp / 18, xx = sp % 18;
    int gy = y0 + yy - 1, gx = x0 + xx - 1;
    uint4 val = make_uint4(0u,0u,0u,0u);
    if (gy>=0 && gy<NH && gx>=0 && gx<NW)
      val = *(const uint4*)(h2 + (((size_t)bg*NH + gy)*NW + gx)*64 + blk*8);
    *(uint4*)&tile[sp][(blk ^ (sp & 7))*8] = val;
  }
  __syncthreads();
  int px = tid & 15, py = tid >> 4;
  float a0 = 0.f, a1 = 0.f;
  #pragma unroll 1
  for (int blk=0;blk<8;blk++){
    #pragma unroll
    for (int dy=0;dy<3;dy++)
    #pragma unroll
    for (int dx=0;dx<3;dx++){
      int sp = (py+dy)*18 + px + dx;
      int tap = dy*3 + dx;
      bf16x8 v8 = *(bf16x8*)&tile[sp][(blk ^ (sp & 7))*8];
      #pragma unroll
      for (int j=0;j<8;j++){
        float v = bfbits2f(v8[j]);
        int ic = blk*8 + j;
        a0 += v * w3s[0][ic*9 + tap];
        a1 += v * w3s[1][ic*9 + tap];
      }
    }
  }
  int gy = y0 + py, gx = x0 + px;
  size_t g = ((size_t)b*NH + gy)*NW + gx;
  float2 xa = xr[g]; float2 xv = xin[g];
  float2 o;
  o.x = xa.x + L2LAMF * (xv.x + a0 + b3[0]);
  o.y = xa.y + L2LAMF * (xv.y + a1 + b3[1]);
  xr[g] = o;
}

// ---------- CG glue ----------
__global__ __launch_bounds__(256) void k_cginit(const float2* __restrict__ rhs,
                                                const float2* __restrict__ Ax0,
                                                const float2* __restrict__ x0,
                                                float2* __restrict__ x,
                                                float2* __restrict__ r,
                                                float2* __restrict__ p,
                                                float* __restrict__ rs){
  __shared__ float red[4];
  int tid = threadIdx.x;
  int b = blockIdx.x / 400; int e = (blockIdx.x % 400)*256 + tid;
  size_t g = (size_t)b*NH*NW + e;
  float2 rh = rhs[g], ax = Ax0[g];
  float2 rv = make_float2(rh.x - ax.x, rh.y - ax.y);
  r[g] = rv; p[g] = rv; x[g] = x0[g];
  float partial = rv.x*rv.x + rv.y*rv.y;
  int lane = tid & 63, wid = tid >> 6;
  #pragma unroll
  for (int o=32;o>0;o>>=1) partial += __shfl_down(partial, o, 64);
  if (lane == 0) red[wid] = partial;
  __syncthreads();
  if (tid == 0) atomicAdd(&rs[b], red[0]+red[1]+red[2]+red[3]);
}

__global__ __launch_bounds__(256) void k_cgupdate(float2* __restrict__ x,
                                                  float2* __restrict__ r,
                                                  const float2* __restrict__ p,
                                                  const float2* __restrict__ Ap,
                                                  const float* __restrict__ rs_old,
                                                  const float* __restrict__ pAp,
                                                  float* __restrict__ rs_new){
  __shared__ float red[4];
  int tid = threadIdx.x;
  int b = blockIdx.x / 400; int e = (blockIdx.x % 400)*256 + tid;
  size_t g = (size_t)b*NH*NW + e;
  float alpha = rs_old[b] / pAp[b];
  float2 xv = x[g], pv = p[g], rv = r[g], av = Ap[g];
  xv.x += alpha*pv.x; xv.y += alpha*pv.y;
  rv.x -= alpha*av.x; rv.y -= alpha*av.y;
  x[g] = xv; r[g] = rv;
  float partial = rv.x*rv.x + rv.y*rv.y;
  int lane = tid & 63, wid = tid >> 6;
  #pragma unroll
  for (int o=32;o>0;o>>=1) partial += __shfl_down(partial, o, 64);
  if (lane == 0) red[wid] = partial;
  __syncthreads();
  if (tid == 0) atomicAdd(&rs_new[b], red[0]+red[1]+red[2]+red[3]);
}

__global__ __launch_bounds__(256) void k_cgp(float2* __restrict__ p,
                                             const float2* __restrict__ r,
                                             const float* __restrict__ rs_new,
                                             const float* __restrict__ rs_old){
  int tid = threadIdx.x;
  int b = blockIdx.x / 400; int e = (blockIdx.x % 400)*256 + tid;
  size_t g = (size_t)b*NH*NW + e;
  float beta = rs_new[b] / rs_old[b];
  float2 rv = r[g], pv = p[g];
  p[g] = make_float2(rv.x + beta*pv.x, rv.y + beta*pv.y);
}

extern "C" void kernel_launch(void* const* d_in, const int* in_sizes, int n_in,
                              void* d_out, int out_size, void* d_ws, size_t ws_size,
                              hipStream_t stream) {
  (void)in_sizes; (void)n_in; (void)out_size;
  const float2* x_in = (const float2*)d_in[0];
  const float2* maps = (const float2*)d_in[1];
  const float*  masks= (const float*)d_in[2];
  const float2* ksp  = (const float2*)d_in[3];
  const float* w1 = (const float*)d_in[4]; const float* b1 = (const float*)d_in[5];
  const float* w2 = (const float*)d_in[6]; const float* b2 = (const float*)d_in[7];
  const float* w3 = (const float*)d_in[8]; const float* b3 = (const float*)d_in[9];
  float2* xout = (float2*)d_out;

  const size_t VECB = (size_t)NB*NH*NW*sizeof(float2);          // 6.55 MB
  const size_t PERB = (size_t)NC*NH*NW*sizeof(float2);          // 9.83 MB (K per batch)
  const size_t HBUF = (size_t)64*NH*NW*sizeof(__hip_bfloat16);  // 13.1 MB (h per batch)
  const size_t WPKB = (size_t)9*64*64*sizeof(__hip_bfloat16);   // 73.7 KB
  auto rnd = [](size_t x){ return (x + 255) & ~(size_t)255; };
  size_t fixed = 4*rnd(VECB) + rnd(4096) + rnd(WPKB);
  int G = 8;
  while (G > 1 && fixed + rnd((size_t)G*PERB) > ws_size) G >>= 1;
  int DEN_G = 8;
  while (DEN_G > 1 &&
         fixed + rnd((size_t)G*PERB > (size_t)DEN_G*2*HBUF ? (size_t)G*PERB
                                                           : (size_t)DEN_G*2*HBUF) > ws_size)
    DEN_G >>= 1;
  size_t region = (size_t)G*PERB;
  if ((size_t)DEN_G*2*HBUF > region) region = (size_t)DEN_G*2*HBUF;

  char* ws = (char*)d_ws;
  size_t off = 0;
  auto alloc = [&](size_t bytes)->void*{ void* p = ws + off; off += rnd(bytes); return p; };
  float2* xr   = (float2*)alloc(VECB);   // xadj -> rhs (in-place)
  float2* Ap   = (float2*)alloc(VECB);
  float2* rbuf = (float2*)alloc(VECB);
  float2* pbuf = (float2*)alloc(VECB);
  float*  scal = (float*)alloc(4096);    // rs[i*8+b]; pAp at +64
  __hip_bfloat16* wpk = (__hip_bfloat16*)alloc(WPKB);
  void*   shrd = alloc(region);          // K during FFT phases; h1/h2 during denoise
  float2* K = (float2*)shrd;
  __hip_bfloat16* h1 = (__hip_bfloat16*)shrd;
  __hip_bfloat16* h2 = h1 + (size_t)DEN_G*64*NH*NW;
  hipMemsetAsync(scal, 0, 4096, stream);

  const int gCol = G*NC*40;
  const int gRow = G*NC*NH/8;
  const int gIC  = G*NH;

  // adjoint: xadj -> xr  (uses K)
  for (int b0 = 0; b0 < NB; b0 += G){
    k_adjCol<<<gCol, 512, 0, stream>>>(ksp, masks, K, b0);
    k_rowIC<false><<<gIC, 256, 0, stream>>>(K, maps, nullptr, xr, nullptr, b0);
  }
  // denoiser: xr = xadj + lam*(x + CNN(x))  (K dead; region holds h1/h2)
  k_prepw2<<<144, 256, 0, stream>>>(w2, wpk);
  for (int b0 = 0; b0 < NB; b0 += DEN_G){
    k_conv1<<<dim3(20,20,DEN_G), 256, 0, stream>>>(x_in, w1, b1, h1, b0);
    k_conv2<<<dim3(40,40,DEN_G), 256, 0, stream>>>(h1, wpk, b2, h2);
    k_conv3<<<dim3(20,20,DEN_G), 256, 0, stream>>>(h2, w3, b3, xr, x_in, b0);
  }
  // Aop(x0) -> Ap
  for (int b0 = 0; b0 < NB; b0 += G){
    k_rowF<<<gRow, 512, 0, stream>>>(x_in, maps, K, b0);
    k_colFMI<<<gCol, 512, 0, stream>>>(K, masks, b0);
    k_rowIC<true><<<gIC, 256, 0, stream>>>(K, maps, x_in, Ap, scal + 64, b0);
  }
  // r = rhs - Ax0; p = r; x = x0; rs0
  k_cginit<<<3200, 256, 0, stream>>>(xr, Ap, x_in, xout, rbuf, pbuf, scal);
  // 6 CG iterations
  for (int i = 1; i <= 6; i++){
    for (int b0 = 0; b0 < NB; b0 += G){
      k_rowF<<<gRow, 512, 0, stream>>>(pbuf, maps, K, b0);
      k_colFMI<<<gCol, 512, 0, stream>>>(K, masks, b0);
      k_rowIC<true><<<gIC, 256, 0, stream>>>(K, maps, pbuf, Ap, scal + 64 + i*8, b0);
    }
    k_cgupdate<<<3200, 256, 0, stream>>>(xout, rbuf, pbuf, Ap,
                                         scal + (i-1)*8, scal + 64 + i*8, scal + i*8);
    if (i < 6)
      k_cgp<<<3200, 256, 0, stream>>>(pbuf, rbuf, scal + i*8, scal + (i-1)*8);
  }
}